// Round 1
// baseline (1314.504 us; speedup 1.0000x reference)
//
#include <hip/hip_runtime.h>

// ---------------------------------------------------------------------------
// GAT 3-layer forward, fp32 baseline.
// Layers: [N,128] -> (GAT 4 heads x 64) -> [N,256] -> (GAT 4x64) -> [N,256]
//         -> (GAT 1x64) -> [N,64]
// Edge set = input edges + self loops (handled inline, e >= E => s=d=e-E).
// Softmax max-subtraction is skipped (mathematically identical, exponents
// bounded ~O(10) with 0.1-scale weights, no fp32 overflow possible).
// ---------------------------------------------------------------------------

#define BM 64
#define BN 64
#define BK 16

__global__ __launch_bounds__(256) void gemm_kernel(
    const float* __restrict__ A, const float* __restrict__ W,
    float* __restrict__ C, int M, int K, int Nc) {
  __shared__ float As[BK][BM + 4];  // +4 keeps 16B row alignment (68*4=272=17*16)
  __shared__ float Ws[BK][BN + 4];
  const int bm = blockIdx.x * BM;
  const int bn = blockIdx.y * BN;
  const int tid = threadIdx.x;
  const int tx = tid & 15;   // col group 0..15
  const int ty = tid >> 4;   // row group 0..15
  float acc[4][4] = {{0.f, 0.f, 0.f, 0.f}, {0.f, 0.f, 0.f, 0.f},
                     {0.f, 0.f, 0.f, 0.f}, {0.f, 0.f, 0.f, 0.f}};
  for (int k0 = 0; k0 < K; k0 += BK) {
    {  // A tile: 64 rows x 16 k, each thread one float4 along k
      const int r = tid & 63;
      const int kq = tid >> 6;  // 0..3
      const int row = bm + r;
      float4 v = make_float4(0.f, 0.f, 0.f, 0.f);
      if (row < M) v = *(const float4*)(A + (size_t)row * K + k0 + kq * 4);
      As[kq * 4 + 0][r] = v.x;
      As[kq * 4 + 1][r] = v.y;
      As[kq * 4 + 2][r] = v.z;
      As[kq * 4 + 3][r] = v.w;
    }
    {  // W tile: 16 k x 64 cols, each thread one float4 along cols
      const int c = (tid & 15) * 4;
      const int kr = tid >> 4;  // 0..15
      float4 v = *(const float4*)(W + (size_t)(k0 + kr) * Nc + bn + c);
      *(float4*)&Ws[kr][c] = v;
    }
    __syncthreads();
#pragma unroll
    for (int k = 0; k < BK; ++k) {
      const float4 a = *(const float4*)&As[k][ty * 4];
      const float4 b = *(const float4*)&Ws[k][tx * 4];
      const float av[4] = {a.x, a.y, a.z, a.w};
      const float bv[4] = {b.x, b.y, b.z, b.w};
#pragma unroll
      for (int i = 0; i < 4; ++i)
#pragma unroll
        for (int j = 0; j < 4; ++j) acc[i][j] = fmaf(av[i], bv[j], acc[i][j]);
    }
    __syncthreads();
  }
#pragma unroll
  for (int i = 0; i < 4; ++i) {
    const int row = bm + ty * 4 + i;
    if (row < M) {
      float4 v = make_float4(acc[i][0], acc[i][1], acc[i][2], acc[i][3]);
      *(float4*)(C + (size_t)row * Nc + bn + tx * 4) = v;
    }
  }
}

// One block per node; blockDim = H*64; wave w reduces head w.
__global__ void attn_coef_kernel(const float* __restrict__ feat,
                                 const float* __restrict__ al,
                                 const float* __restrict__ ar,
                                 float* __restrict__ el, float* __restrict__ er,
                                 int H) {
  const int n = blockIdx.x;
  const int t = threadIdx.x;
  const int HF = blockDim.x;
  const float v = feat[(size_t)n * HF + t];
  float pl = v * al[t];
  float pr = v * ar[t];
#pragma unroll
  for (int off = 32; off > 0; off >>= 1) {
    pl += __shfl_down(pl, off);
    pr += __shfl_down(pr, off);
  }
  if ((t & 63) == 0) {
    el[n * H + (t >> 6)] = pl;
    er[n * H + (t >> 6)] = pr;
  }
}

__global__ void edge_denom_kernel(const int* __restrict__ src,
                                  const int* __restrict__ dst,
                                  const float* __restrict__ el,
                                  const float* __restrict__ er,
                                  float* __restrict__ ex,
                                  float* __restrict__ denom, int E, int Nn,
                                  int H) {
  const int e = blockIdx.x * blockDim.x + threadIdx.x;
  const int ET = E + Nn;
  if (e >= ET) return;
  const int s = (e < E) ? src[e] : (e - E);
  const int d = (e < E) ? dst[e] : (e - E);
  for (int h = 0; h < H; ++h) {
    const float x = el[s * H + h] + er[d * H + h];
    const float lr = (x > 0.f) ? x : 0.2f * x;
    const float v = __expf(lr);
    ex[e * H + h] = v;
    atomicAdd(&denom[d * H + h], v);
  }
}

__global__ void rcp_kernel(float* __restrict__ denom, int n) {
  const int i = blockIdx.x * blockDim.x + threadIdx.x;
  if (i < n) denom[i] = 1.0f / denom[i];
}

__global__ void init_bias_kernel(float* __restrict__ out,
                                 const float* __restrict__ b, int total,
                                 int mask) {
  const int i = blockIdx.x * blockDim.x + threadIdx.x;
  if (i < total) out[i] = b[i & mask];
}

// One wave per edge; lanes stride the H*64 feature row.
__global__ __launch_bounds__(256) void aggregate_kernel(
    const int* __restrict__ src, const int* __restrict__ dst,
    const float* __restrict__ feat, const float* __restrict__ ex,
    const float* __restrict__ rdenom, float* __restrict__ out, int E, int Nn,
    int HF, int H) {
  const int gid = blockIdx.x * blockDim.x + threadIdx.x;
  const int e = gid >> 6;
  const int lane = gid & 63;
  const int ET = E + Nn;
  if (e >= ET) return;
  const int s = (e < E) ? src[e] : (e - E);
  const int d = (e < E) ? dst[e] : (e - E);
  const float* frow = feat + (size_t)s * HF;
  float* orow = out + (size_t)d * HF;
  int h = 0;
  for (int c = lane; c < HF; c += 64, ++h) {
    const float alpha = ex[e * H + h] * rdenom[d * H + h];
    atomicAdd(&orow[c], frow[c] * alpha);
  }
}

static void run_layer(const float* hin, int K, int H, const float* W,
                      const float* al, const float* ar, const float* b,
                      float* feat, float* out, float* el, float* er, float* ex,
                      float* denom, const int* src, const int* dst, int Nn,
                      int E, hipStream_t stream) {
  const int HF = H * 64;
  const int ET = E + Nn;
  dim3 gg((Nn + BM - 1) / BM, HF / BN);
  gemm_kernel<<<gg, 256, 0, stream>>>(hin, W, feat, Nn, K, HF);
  attn_coef_kernel<<<Nn, HF, 0, stream>>>(feat, al, ar, el, er, H);
  hipMemsetAsync(denom, 0, (size_t)Nn * H * sizeof(float), stream);
  edge_denom_kernel<<<(ET + 255) / 256, 256, 0, stream>>>(src, dst, el, er, ex,
                                                          denom, E, Nn, H);
  rcp_kernel<<<(Nn * H + 255) / 256, 256, 0, stream>>>(denom, Nn * H);
  const int total = Nn * HF;
  init_bias_kernel<<<(total + 255) / 256, 256, 0, stream>>>(out, b, total,
                                                            HF - 1);
  const long long nthreads = (long long)ET * 64;
  aggregate_kernel<<<(int)((nthreads + 255) / 256), 256, 0, stream>>>(
      src, dst, feat, ex, denom, out, E, Nn, HF, H);
}

extern "C" void kernel_launch(void* const* d_in, const int* in_sizes, int n_in,
                              void* d_out, int out_size, void* d_ws,
                              size_t ws_size, hipStream_t stream) {
  const float* nf = (const float*)d_in[0];
  const int* src = (const int*)d_in[1];
  const int* dst = (const int*)d_in[2];
  const float* W0 = (const float*)d_in[3];
  const float* al0 = (const float*)d_in[4];
  const float* ar0 = (const float*)d_in[5];
  const float* b0 = (const float*)d_in[6];
  const float* W1 = (const float*)d_in[7];
  const float* al1 = (const float*)d_in[8];
  const float* ar1 = (const float*)d_in[9];
  const float* b1 = (const float*)d_in[10];
  const float* W2 = (const float*)d_in[11];
  const float* al2 = (const float*)d_in[12];
  const float* ar2 = (const float*)d_in[13];
  const float* b2 = (const float*)d_in[14];

  const int IN = 128;
  const int Nn = in_sizes[0] / IN;
  const int E = in_sizes[1];
  const int ET = E + Nn;

  float* ws = (float*)d_ws;
  size_t off = 0;
  auto alloc = [&](size_t n) {
    float* p = ws + off;
    off += (n + 63) & ~(size_t)63;
    return p;
  };
  float* feat = alloc((size_t)Nn * 256);
  float* h1 = alloc((size_t)Nn * 256);
  float* h2 = alloc((size_t)Nn * 256);
  float* el = alloc((size_t)Nn * 4);
  float* er = alloc((size_t)Nn * 4);
  float* denom = alloc((size_t)Nn * 4);
  float* ex = alloc((size_t)ET * 4);
  (void)ws_size;
  (void)n_in;
  (void)out_size;

  // Layer 0: [N,128] -> [N,256]
  run_layer(nf, IN, 4, W0, al0, ar0, b0, feat, h1, el, er, ex, denom, src, dst,
            Nn, E, stream);
  // Layer 1: [N,256] -> [N,256]
  run_layer(h1, 256, 4, W1, al1, ar1, b1, feat, h2, el, er, ex, denom, src,
            dst, Nn, E, stream);
  // Layer 2: [N,256] -> [N,64]
  run_layer(h2, 256, 1, W2, al2, ar2, b2, feat, (float*)d_out, el, er, ex,
            denom, src, dst, Nn, E, stream);
}

// Round 2
// 684.334 us; speedup vs baseline: 1.9209x; 1.9209x over previous
//
#include <hip/hip_runtime.h>

// ---------------------------------------------------------------------------
// GAT 3-layer forward, fp32, CSR pull-based aggregation (no float atomics).
// dst is layer-invariant: build CSR once (hist -> scan -> scatter), reuse 3x.
// Per dest node: denom = wave-reduced sum of exp(leaky(el[s]+er[n])); out row
// written exactly once: out = (sum ex*feat[src]) * (1/denom) + bias.
// Softmax max-subtraction skipped (bounded exponents, fp32 safe).
// ---------------------------------------------------------------------------

#define BM 64
#define BN 64
#define BK 16

__global__ __launch_bounds__(256) void gemm_kernel(
    const float* __restrict__ A, const float* __restrict__ W,
    float* __restrict__ C, int M, int K, int Nc) {
  __shared__ float As[BK][BM + 4];
  __shared__ float Ws[BK][BN + 4];
  const int bm = blockIdx.x * BM;
  const int bn = blockIdx.y * BN;
  const int tid = threadIdx.x;
  const int tx = tid & 15;
  const int ty = tid >> 4;
  float acc[4][4] = {{0.f, 0.f, 0.f, 0.f}, {0.f, 0.f, 0.f, 0.f},
                     {0.f, 0.f, 0.f, 0.f}, {0.f, 0.f, 0.f, 0.f}};
  for (int k0 = 0; k0 < K; k0 += BK) {
    {
      const int r = tid & 63;
      const int kq = tid >> 6;
      const int row = bm + r;
      float4 v = make_float4(0.f, 0.f, 0.f, 0.f);
      if (row < M) v = *(const float4*)(A + (size_t)row * K + k0 + kq * 4);
      As[kq * 4 + 0][r] = v.x;
      As[kq * 4 + 1][r] = v.y;
      As[kq * 4 + 2][r] = v.z;
      As[kq * 4 + 3][r] = v.w;
    }
    {
      const int c = (tid & 15) * 4;
      const int kr = tid >> 4;
      float4 v = *(const float4*)(W + (size_t)(k0 + kr) * Nc + bn + c);
      *(float4*)&Ws[kr][c] = v;
    }
    __syncthreads();
#pragma unroll
    for (int k = 0; k < BK; ++k) {
      const float4 a = *(const float4*)&As[k][ty * 4];
      const float4 b = *(const float4*)&Ws[k][tx * 4];
      const float av[4] = {a.x, a.y, a.z, a.w};
      const float bv[4] = {b.x, b.y, b.z, b.w};
#pragma unroll
      for (int i = 0; i < 4; ++i)
#pragma unroll
        for (int j = 0; j < 4; ++j) acc[i][j] = fmaf(av[i], bv[j], acc[i][j]);
    }
    __syncthreads();
  }
#pragma unroll
  for (int i = 0; i < 4; ++i) {
    const int row = bm + ty * 4 + i;
    if (row < M) {
      float4 v = make_float4(acc[i][0], acc[i][1], acc[i][2], acc[i][3]);
      *(float4*)(C + (size_t)row * Nc + bn + tx * 4) = v;
    }
  }
}

// One block per node; blockDim = H*64; wave w reduces head w.
__global__ void attn_coef_kernel(const float* __restrict__ feat,
                                 const float* __restrict__ al,
                                 const float* __restrict__ ar,
                                 float* __restrict__ el, float* __restrict__ er,
                                 int H) {
  const int n = blockIdx.x;
  const int t = threadIdx.x;
  const int HF = blockDim.x;
  const float v = feat[(size_t)n * HF + t];
  float pl = v * al[t];
  float pr = v * ar[t];
#pragma unroll
  for (int off = 32; off > 0; off >>= 1) {
    pl += __shfl_down(pl, off);
    pr += __shfl_down(pr, off);
  }
  if ((t & 63) == 0) {
    el[n * H + (t >> 6)] = pl;
    er[n * H + (t >> 6)] = pr;
  }
}

// ------------------------- CSR construction -------------------------------
__global__ void hist_kernel(const int* __restrict__ dst, int* __restrict__ cnt,
                            int E, int Nn) {
  const int e = blockIdx.x * blockDim.x + threadIdx.x;
  if (e >= E + Nn) return;
  const int d = (e < E) ? dst[e] : (e - E);
  atomicAdd(&cnt[d], 1);
}

__global__ __launch_bounds__(1024) void scan_kernel(const int* __restrict__ cnt,
                                                    int* __restrict__ row_ptr,
                                                    int* __restrict__ cursor,
                                                    int n) {
  __shared__ int buf[1024];
  __shared__ int carry;
  const int t = threadIdx.x;
  if (t == 0) carry = 0;
  __syncthreads();
  for (int base = 0; base < n; base += 1024) {
    const int i = base + t;
    const int x = (i < n) ? cnt[i] : 0;
    buf[t] = x;
    __syncthreads();
#pragma unroll
    for (int off = 1; off < 1024; off <<= 1) {
      const int v = (t >= off) ? buf[t - off] : 0;
      __syncthreads();
      buf[t] += v;
      __syncthreads();
    }
    const int excl = buf[t] - x + carry;
    if (i < n) {
      row_ptr[i] = excl;
      cursor[i] = excl;
    }
    __syncthreads();
    if (t == 1023) carry += buf[1023];
    __syncthreads();
  }
  if (t == 0) row_ptr[n] = carry;
}

__global__ void scatter_kernel(const int* __restrict__ src,
                               const int* __restrict__ dst,
                               int* __restrict__ cursor, int* __restrict__ esrc,
                               int E, int Nn) {
  const int e = blockIdx.x * blockDim.x + threadIdx.x;
  if (e >= E + Nn) return;
  const int s = (e < E) ? src[e] : (e - E);
  const int d = (e < E) ? dst[e] : (e - E);
  const int pos = atomicAdd(&cursor[d], 1);
  esrc[pos] = s;
}

// --------------------- edge softmax (pull, no atomics) --------------------
template <int H>
__global__ __launch_bounds__(256) void edge_softmax_csr(
    const int* __restrict__ row_ptr, const int* __restrict__ esrc,
    const float* __restrict__ el, const float* __restrict__ er,
    float* __restrict__ exs, float* __restrict__ rdenom, int Nn) {
  const int wid = (blockIdx.x * 256 + threadIdx.x) >> 6;
  const int lane = threadIdx.x & 63;
  if (wid >= Nn) return;
  const int n = wid;
  const int start = row_ptr[n];
  const int deg = row_ptr[n + 1] - start;
  const int h = (H == 4) ? (lane & 3) : 0;
  const float erv = er[n * H + h];
  float part = 0.f;
  for (int idx = lane; idx < deg * H; idx += 64) {
    const int i = (H == 4) ? (idx >> 2) : idx;
    const int s = esrc[start + i];
    float x = el[s * H + h] + erv;
    x = (x > 0.f) ? x : 0.2f * x;
    const float v = __expf(x);
    exs[(start + i) * H + h] = v;
    part += v;
  }
  if (H == 4) {
    part += __shfl_xor(part, 4);
    part += __shfl_xor(part, 8);
    part += __shfl_xor(part, 16);
    part += __shfl_xor(part, 32);
    if (lane < 4) rdenom[n * 4 + lane] = 1.f / part;
  } else {
#pragma unroll
    for (int off = 1; off < 64; off <<= 1) part += __shfl_xor(part, off);
    if (lane == 0) rdenom[n] = 1.f / part;
  }
}

// --------------------- aggregation (pull, no atomics) ---------------------
// HF=256 (H=4): one block (256 thr) per node; thread owns one channel.
__global__ __launch_bounds__(256) void aggregate_csr_h4(
    const int* __restrict__ row_ptr, const int* __restrict__ esrc,
    const float* __restrict__ exs, const float* __restrict__ rdenom,
    const float* __restrict__ feat, const float* __restrict__ b,
    float* __restrict__ out, int Nn) {
  const int n = blockIdx.x;
  const int c = threadIdx.x;
  const int h = c >> 6;
  const int start = row_ptr[n];
  const int end = row_ptr[n + 1];
  float acc = 0.f;
  for (int i = start; i < end; ++i) {
    const int s = esrc[i];
    const float v = exs[i * 4 + h];
    acc += v * feat[(size_t)s * 256 + c];
  }
  out[(size_t)n * 256 + c] = acc * rdenom[n * 4 + h] + b[c];
}

// HF=64 (H=1): one wave per node.
__global__ __launch_bounds__(256) void aggregate_csr_h1(
    const int* __restrict__ row_ptr, const int* __restrict__ esrc,
    const float* __restrict__ exs, const float* __restrict__ rdenom,
    const float* __restrict__ feat, const float* __restrict__ b,
    float* __restrict__ out, int Nn) {
  const int wid = (blockIdx.x * 256 + threadIdx.x) >> 6;
  const int lane = threadIdx.x & 63;
  if (wid >= Nn) return;
  const int n = wid;
  const int start = row_ptr[n];
  const int end = row_ptr[n + 1];
  float acc = 0.f;
  for (int i = start; i < end; ++i) {
    const int s = esrc[i];
    acc += exs[i] * feat[(size_t)s * 64 + lane];
  }
  out[(size_t)n * 64 + lane] = acc * rdenom[n] + b[lane];
}

static void run_layer(const float* hin, int K, int H, const float* W,
                      const float* al, const float* ar, const float* b,
                      float* feat, float* out, float* el, float* er,
                      float* exs, float* rdenom, const int* row_ptr,
                      const int* esrc, int Nn, hipStream_t stream) {
  const int HF = H * 64;
  dim3 gg((Nn + BM - 1) / BM, HF / BN);
  gemm_kernel<<<gg, 256, 0, stream>>>(hin, W, feat, Nn, K, HF);
  attn_coef_kernel<<<Nn, HF, 0, stream>>>(feat, al, ar, el, er, H);
  const int waves_grid = (Nn * 64 + 255) / 256;
  if (H == 4) {
    edge_softmax_csr<4><<<waves_grid, 256, 0, stream>>>(row_ptr, esrc, el, er,
                                                        exs, rdenom, Nn);
    aggregate_csr_h4<<<Nn, 256, 0, stream>>>(row_ptr, esrc, exs, rdenom, feat,
                                             b, out, Nn);
  } else {
    edge_softmax_csr<1><<<waves_grid, 256, 0, stream>>>(row_ptr, esrc, el, er,
                                                        exs, rdenom, Nn);
    aggregate_csr_h1<<<waves_grid, 256, 0, stream>>>(row_ptr, esrc, exs,
                                                     rdenom, feat, b, out, Nn);
  }
}

extern "C" void kernel_launch(void* const* d_in, const int* in_sizes, int n_in,
                              void* d_out, int out_size, void* d_ws,
                              size_t ws_size, hipStream_t stream) {
  const float* nf = (const float*)d_in[0];
  const int* src = (const int*)d_in[1];
  const int* dst = (const int*)d_in[2];
  const float* W0 = (const float*)d_in[3];
  const float* al0 = (const float*)d_in[4];
  const float* ar0 = (const float*)d_in[5];
  const float* b0 = (const float*)d_in[6];
  const float* W1 = (const float*)d_in[7];
  const float* al1 = (const float*)d_in[8];
  const float* ar1 = (const float*)d_in[9];
  const float* b1 = (const float*)d_in[10];
  const float* W2 = (const float*)d_in[11];
  const float* al2 = (const float*)d_in[12];
  const float* ar2 = (const float*)d_in[13];
  const float* b2 = (const float*)d_in[14];

  const int IN = 128;
  const int Nn = in_sizes[0] / IN;
  const int E = in_sizes[1];
  const int ET = E + Nn;

  float* ws = (float*)d_ws;
  size_t off = 0;
  auto alloc = [&](size_t n) {
    float* p = ws + off;
    off += (n + 63) & ~(size_t)63;
    return p;
  };
  float* feat = alloc((size_t)Nn * 256);
  float* h1 = alloc((size_t)Nn * 256);
  float* h2 = alloc((size_t)Nn * 256);
  float* el = alloc((size_t)Nn * 4);
  float* er = alloc((size_t)Nn * 4);
  float* rdenom = alloc((size_t)Nn * 4);
  float* exs = alloc((size_t)ET * 4);
  int* row_ptr = (int*)alloc((size_t)Nn + 1);
  int* cnt = (int*)alloc((size_t)Nn);
  int* cursor = (int*)alloc((size_t)Nn);
  int* esrc = (int*)alloc((size_t)ET);
  (void)ws_size;
  (void)n_in;
  (void)out_size;

  // ---- Build CSR over dst (reused by all 3 layers) ----
  hipMemsetAsync(cnt, 0, (size_t)Nn * sizeof(int), stream);
  hist_kernel<<<(ET + 255) / 256, 256, 0, stream>>>(dst, cnt, E, Nn);
  scan_kernel<<<1, 1024, 0, stream>>>(cnt, row_ptr, cursor, Nn);
  scatter_kernel<<<(ET + 255) / 256, 256, 0, stream>>>(src, dst, cursor, esrc,
                                                       E, Nn);

  // Layer 0: [N,128] -> [N,256]
  run_layer(nf, IN, 4, W0, al0, ar0, b0, feat, h1, el, er, exs, rdenom,
            row_ptr, esrc, Nn, stream);
  // Layer 1: [N,256] -> [N,256]
  run_layer(h1, 256, 4, W1, al1, ar1, b1, feat, h2, el, er, exs, rdenom,
            row_ptr, esrc, Nn, stream);
  // Layer 2: [N,256] -> [N,64]
  run_layer(h2, 256, 1, W2, al2, ar2, b2, feat, (float*)d_out, el, er, exs,
            rdenom, row_ptr, esrc, Nn, stream);
}

// Round 3
// 489.702 us; speedup vs baseline: 2.6843x; 1.3975x over previous
//
#include <hip/hip_runtime.h>

// ---------------------------------------------------------------------------
// GAT 3-layer forward. bf16 MFMA GEMMs + bf16 feat for the edge gather.
// CSR pull-based aggregation (no float atomics), CSR built once, reused 3x.
// Softmax max-subtraction skipped (bounded exponents, fp32 exp safe).
// ---------------------------------------------------------------------------

typedef __attribute__((ext_vector_type(8))) short short8;
typedef __attribute__((ext_vector_type(4))) float f32x4;

__device__ __forceinline__ float bf2f(ushort u) {
  union { unsigned int i; float f; } c;
  c.i = ((unsigned int)u) << 16;
  return c.f;
}
__device__ __forceinline__ ushort f2bf(float f) {
  union { float f; unsigned int i; } c;
  c.f = f;
  unsigned int u = c.i;
  u += 0x7FFFu + ((u >> 16) & 1u);
  return (ushort)(u >> 16);
}

// ------------------------- weight transpose+convert ------------------------
// W fp32 [K][N] -> Wt bf16 [N][K]
__global__ void convert_w_kernel(const float* __restrict__ W,
                                 ushort* __restrict__ Wt, int K, int N) {
  const int i = blockIdx.x * 256 + threadIdx.x;
  if (i >= K * N) return;
  const int k = i / N, n = i - k * N;
  Wt[n * K + k] = f2bf(W[i]);
}

// ------------------------------ bf16 GEMM ----------------------------------
// A [M][K] (fp32 if AF32 else bf16), Wt [Nc][K] bf16 -> C [M][Nc] bf16.
// BM=128 BN=64 BK=32, 256 threads = 4 waves (2x2), wave tile 64x32,
// per wave 4x2 fragments of mfma_f32_16x16x32_bf16.
template <bool AF32>
__global__ __launch_bounds__(256) void gemm_bf16_kernel(
    const void* __restrict__ Ap, const ushort* __restrict__ Wt,
    ushort* __restrict__ C, int M, int K, int Nc) {
  __shared__ ushort As[128][40];  // +8 pad: 80B row stride -> 2-way (free)
  __shared__ ushort Bs[64][40];
  const int bm = blockIdx.x * 128;
  const int bn = blockIdx.y * 64;
  const int tid = threadIdx.x;
  const int lane = tid & 63;
  const int wave = tid >> 6;
  const int wm = wave >> 1;  // 0..1
  const int wn = wave & 1;   // 0..1
  const int ar = tid >> 1;          // A stage row 0..127
  const int ac = (tid & 1) * 16;    // A stage col 0 or 16
  const int brow = tid >> 2;        // B stage n 0..63
  const int bk = (tid & 3) * 8;     // B stage k 0..24
  const bool a_ok = (bm + ar) < M;

  f32x4 acc[4][2];
#pragma unroll
  for (int m = 0; m < 4; ++m)
#pragma unroll
    for (int n = 0; n < 2; ++n) acc[m][n] = 0.f;

  for (int k0 = 0; k0 < K; k0 += 32) {
    short8 h0, h1;
    if (AF32) {
      const float* A = (const float*)Ap;
      float buf[16];
      if (a_ok) {
        const float* p = A + (size_t)(bm + ar) * K + k0 + ac;
#pragma unroll
        for (int q = 0; q < 4; ++q) {
          float4 v = *(const float4*)(p + q * 4);
          buf[q * 4 + 0] = v.x;
          buf[q * 4 + 1] = v.y;
          buf[q * 4 + 2] = v.z;
          buf[q * 4 + 3] = v.w;
        }
      } else {
#pragma unroll
        for (int q = 0; q < 16; ++q) buf[q] = 0.f;
      }
#pragma unroll
      for (int q = 0; q < 8; ++q) h0[q] = (short)f2bf(buf[q]);
#pragma unroll
      for (int q = 0; q < 8; ++q) h1[q] = (short)f2bf(buf[8 + q]);
    } else {
      const ushort* A = (const ushort*)Ap;
      if (a_ok) {
        const ushort* p = A + (size_t)(bm + ar) * K + k0 + ac;
        h0 = *(const short8*)p;
        h1 = *(const short8*)(p + 8);
      } else {
        h0 = 0;
        h1 = 0;
      }
    }
    *(short8*)&As[ar][ac] = h0;
    *(short8*)&As[ar][ac + 8] = h1;
    *(short8*)&Bs[brow][bk] =
        *(const short8*)(Wt + (size_t)(bn + brow) * K + k0 + bk);
    __syncthreads();

    short8 a[4], b[2];
#pragma unroll
    for (int m = 0; m < 4; ++m)
      a[m] = *(const short8*)&As[wm * 64 + m * 16 + (lane & 15)][(lane >> 4) * 8];
#pragma unroll
    for (int n = 0; n < 2; ++n)
      b[n] = *(const short8*)&Bs[wn * 32 + n * 16 + (lane & 15)][(lane >> 4) * 8];
#pragma unroll
    for (int m = 0; m < 4; ++m)
#pragma unroll
      for (int n = 0; n < 2; ++n)
        acc[m][n] = __builtin_amdgcn_mfma_f32_16x16x32_bf16(a[m], b[n],
                                                            acc[m][n], 0, 0, 0);
    __syncthreads();
  }

#pragma unroll
  for (int m = 0; m < 4; ++m) {
#pragma unroll
    for (int r = 0; r < 4; ++r) {
      const int row = bm + wm * 64 + m * 16 + (lane >> 4) * 4 + r;
      if (row < M) {
#pragma unroll
        for (int n = 0; n < 2; ++n) {
          const int col = bn + wn * 32 + n * 16 + (lane & 15);
          C[(size_t)row * Nc + col] = f2bf(acc[m][n][r]);
        }
      }
    }
  }
}

// One block per node; blockDim = H*64; wave w reduces head w.
__global__ void attn_coef_kernel(const ushort* __restrict__ feat,
                                 const float* __restrict__ al,
                                 const float* __restrict__ ar,
                                 float* __restrict__ el, float* __restrict__ er,
                                 int H) {
  const int n = blockIdx.x;
  const int t = threadIdx.x;
  const int HF = blockDim.x;
  const float v = bf2f(feat[(size_t)n * HF + t]);
  float pl = v * al[t];
  float pr = v * ar[t];
#pragma unroll
  for (int off = 32; off > 0; off >>= 1) {
    pl += __shfl_down(pl, off);
    pr += __shfl_down(pr, off);
  }
  if ((t & 63) == 0) {
    el[n * H + (t >> 6)] = pl;
    er[n * H + (t >> 6)] = pr;
  }
}

// ------------------------- CSR construction -------------------------------
__global__ void hist_kernel(const int* __restrict__ dst, int* __restrict__ cnt,
                            int E, int Nn) {
  const int e = blockIdx.x * blockDim.x + threadIdx.x;
  if (e >= E + Nn) return;
  const int d = (e < E) ? dst[e] : (e - E);
  atomicAdd(&cnt[d], 1);
}

__global__ __launch_bounds__(1024) void scan_kernel(const int* __restrict__ cnt,
                                                    int* __restrict__ row_ptr,
                                                    int* __restrict__ cursor,
                                                    int n) {
  __shared__ int buf[1024];
  __shared__ int carry;
  const int t = threadIdx.x;
  if (t == 0) carry = 0;
  __syncthreads();
  for (int base = 0; base < n; base += 1024) {
    const int i = base + t;
    const int x = (i < n) ? cnt[i] : 0;
    buf[t] = x;
    __syncthreads();
#pragma unroll
    for (int off = 1; off < 1024; off <<= 1) {
      const int v = (t >= off) ? buf[t - off] : 0;
      __syncthreads();
      buf[t] += v;
      __syncthreads();
    }
    const int excl = buf[t] - x + carry;
    if (i < n) {
      row_ptr[i] = excl;
      cursor[i] = excl;
    }
    __syncthreads();
    if (t == 1023) carry += buf[1023];
    __syncthreads();
  }
  if (t == 0) row_ptr[n] = carry;
}

__global__ void scatter_kernel(const int* __restrict__ src,
                               const int* __restrict__ dst,
                               int* __restrict__ cursor, int* __restrict__ esrc,
                               int E, int Nn) {
  const int e = blockIdx.x * blockDim.x + threadIdx.x;
  if (e >= E + Nn) return;
  const int s = (e < E) ? src[e] : (e - E);
  const int d = (e < E) ? dst[e] : (e - E);
  const int pos = atomicAdd(&cursor[d], 1);
  esrc[pos] = s;
}

// --------------------- edge softmax (pull, no atomics) --------------------
template <int H>
__global__ __launch_bounds__(256) void edge_softmax_csr(
    const int* __restrict__ row_ptr, const int* __restrict__ esrc,
    const float* __restrict__ el, const float* __restrict__ er,
    float* __restrict__ exs, float* __restrict__ rdenom, int Nn) {
  const int wid = (blockIdx.x * 256 + threadIdx.x) >> 6;
  const int lane = threadIdx.x & 63;
  if (wid >= Nn) return;
  const int n = wid;
  const int start = row_ptr[n];
  const int deg = row_ptr[n + 1] - start;
  const int h = (H == 4) ? (lane & 3) : 0;
  const float erv = er[n * H + h];
  float part = 0.f;
  for (int idx = lane; idx < deg * H; idx += 64) {
    const int i = (H == 4) ? (idx >> 2) : idx;
    const int s = esrc[start + i];
    float x = el[s * H + h] + erv;
    x = (x > 0.f) ? x : 0.2f * x;
    const float v = __expf(x);
    exs[(start + i) * H + h] = v;
    part += v;
  }
  if (H == 4) {
    part += __shfl_xor(part, 4);
    part += __shfl_xor(part, 8);
    part += __shfl_xor(part, 16);
    part += __shfl_xor(part, 32);
    if (lane < 4) rdenom[n * 4 + lane] = 1.f / part;
  } else {
#pragma unroll
    for (int off = 1; off < 64; off <<= 1) part += __shfl_xor(part, off);
    if (lane == 0) rdenom[n] = 1.f / part;
  }
}

// --------------------- aggregation (pull, no atomics) ---------------------
// HF=256 (H=4): one block (256 thr) per node; thread owns one channel.
// bf16 feat in, bf16 out (next layer's GEMM A).
__global__ __launch_bounds__(256) void aggregate_csr_h4(
    const int* __restrict__ row_ptr, const int* __restrict__ esrc,
    const float* __restrict__ exs, const float* __restrict__ rdenom,
    const ushort* __restrict__ feat, const float* __restrict__ b,
    ushort* __restrict__ out, int Nn) {
  const int n = blockIdx.x;
  const int c = threadIdx.x;
  const int h = c >> 6;
  const int start = row_ptr[n];
  const int end = row_ptr[n + 1];
  float acc = 0.f;
  int i = start;
  for (; i + 1 < end; i += 2) {
    const int s0 = esrc[i];
    const int s1 = esrc[i + 1];
    const float v0 = exs[i * 4 + h];
    const float v1 = exs[(i + 1) * 4 + h];
    const float f0 = bf2f(feat[(size_t)s0 * 256 + c]);
    const float f1 = bf2f(feat[(size_t)s1 * 256 + c]);
    acc = fmaf(v0, f0, acc);
    acc = fmaf(v1, f1, acc);
  }
  if (i < end) {
    const int s = esrc[i];
    acc = fmaf(exs[i * 4 + h], bf2f(feat[(size_t)s * 256 + c]), acc);
  }
  out[(size_t)n * 256 + c] = f2bf(acc * rdenom[n * 4 + h] + b[c]);
}

// HF=64 (H=1): one wave per node; fp32 output (final layer -> d_out).
__global__ __launch_bounds__(256) void aggregate_csr_h1(
    const int* __restrict__ row_ptr, const int* __restrict__ esrc,
    const float* __restrict__ exs, const float* __restrict__ rdenom,
    const ushort* __restrict__ feat, const float* __restrict__ b,
    float* __restrict__ out, int Nn) {
  const int wid = (blockIdx.x * 256 + threadIdx.x) >> 6;
  const int lane = threadIdx.x & 63;
  if (wid >= Nn) return;
  const int n = wid;
  const int start = row_ptr[n];
  const int end = row_ptr[n + 1];
  float acc = 0.f;
  int i = start;
  for (; i + 1 < end; i += 2) {
    const int s0 = esrc[i];
    const int s1 = esrc[i + 1];
    const float f0 = bf2f(feat[(size_t)s0 * 64 + lane]);
    const float f1 = bf2f(feat[(size_t)s1 * 64 + lane]);
    acc = fmaf(exs[i], f0, acc);
    acc = fmaf(exs[i + 1], f1, acc);
  }
  if (i < end) acc = fmaf(exs[i], bf2f(feat[(size_t)esrc[i] * 64 + lane]), acc);
  out[(size_t)n * 64 + lane] = acc * rdenom[n] + b[lane];
}

// ------------------------------- driver -----------------------------------
static void run_layer(const void* hin, bool af32, int K, int H, const float* W,
                      const float* al, const float* ar, const float* b,
                      ushort* Wt, ushort* feat, void* out, bool out_f32,
                      float* el, float* er, float* exs, float* rdenom,
                      const int* row_ptr, const int* esrc, int Nn,
                      hipStream_t stream) {
  const int HF = H * 64;
  convert_w_kernel<<<(K * HF + 255) / 256, 256, 0, stream>>>(W, Wt, K, HF);
  dim3 gg((Nn + 127) / 128, HF / 64);
  if (af32)
    gemm_bf16_kernel<true><<<gg, 256, 0, stream>>>(hin, Wt, feat, Nn, K, HF);
  else
    gemm_bf16_kernel<false><<<gg, 256, 0, stream>>>(hin, Wt, feat, Nn, K, HF);
  attn_coef_kernel<<<Nn, HF, 0, stream>>>(feat, al, ar, el, er, H);
  const int waves_grid = (Nn * 64 + 255) / 256;
  if (H == 4) {
    edge_softmax_csr<4><<<waves_grid, 256, 0, stream>>>(row_ptr, esrc, el, er,
                                                        exs, rdenom, Nn);
    aggregate_csr_h4<<<Nn, 256, 0, stream>>>(row_ptr, esrc, exs, rdenom, feat,
                                             b, (ushort*)out, Nn);
  } else {
    edge_softmax_csr<1><<<waves_grid, 256, 0, stream>>>(row_ptr, esrc, el, er,
                                                        exs, rdenom, Nn);
    aggregate_csr_h1<<<waves_grid, 256, 0, stream>>>(
        row_ptr, esrc, exs, rdenom, feat, b, (float*)out, Nn);
  }
  (void)out_f32;
}

extern "C" void kernel_launch(void* const* d_in, const int* in_sizes, int n_in,
                              void* d_out, int out_size, void* d_ws,
                              size_t ws_size, hipStream_t stream) {
  const float* nf = (const float*)d_in[0];
  const int* src = (const int*)d_in[1];
  const int* dst = (const int*)d_in[2];
  const float* W0 = (const float*)d_in[3];
  const float* al0 = (const float*)d_in[4];
  const float* ar0 = (const float*)d_in[5];
  const float* b0 = (const float*)d_in[6];
  const float* W1 = (const float*)d_in[7];
  const float* al1 = (const float*)d_in[8];
  const float* ar1 = (const float*)d_in[9];
  const float* b1 = (const float*)d_in[10];
  const float* W2 = (const float*)d_in[11];
  const float* al2 = (const float*)d_in[12];
  const float* ar2 = (const float*)d_in[13];
  const float* b2 = (const float*)d_in[14];

  const int IN = 128;
  const int Nn = in_sizes[0] / IN;
  const int E = in_sizes[1];
  const int ET = E + Nn;

  char* ws = (char*)d_ws;
  size_t off = 0;
  auto alloc = [&](size_t bytes) {
    char* p = ws + off;
    off += (bytes + 255) & ~(size_t)255;
    return p;
  };
  ushort* feat = (ushort*)alloc((size_t)Nn * 256 * 2);
  ushort* h1 = (ushort*)alloc((size_t)Nn * 256 * 2);
  ushort* h2 = (ushort*)alloc((size_t)Nn * 256 * 2);
  ushort* Wt = (ushort*)alloc((size_t)256 * 256 * 2);
  float* el = (float*)alloc((size_t)Nn * 4 * 4);
  float* er = (float*)alloc((size_t)Nn * 4 * 4);
  float* rdenom = (float*)alloc((size_t)Nn * 4 * 4);
  float* exs = (float*)alloc((size_t)ET * 4 * 4);
  int* row_ptr = (int*)alloc(((size_t)Nn + 1) * 4);
  int* cnt = (int*)alloc((size_t)Nn * 4);
  int* cursor = (int*)alloc((size_t)Nn * 4);
  int* esrc = (int*)alloc((size_t)ET * 4);
  (void)ws_size;
  (void)n_in;
  (void)out_size;

  // ---- Build CSR over dst (reused by all 3 layers) ----
  hipMemsetAsync(cnt, 0, (size_t)Nn * sizeof(int), stream);
  hist_kernel<<<(ET + 255) / 256, 256, 0, stream>>>(dst, cnt, E, Nn);
  scan_kernel<<<1, 1024, 0, stream>>>(cnt, row_ptr, cursor, Nn);
  scatter_kernel<<<(ET + 255) / 256, 256, 0, stream>>>(src, dst, cursor, esrc,
                                                       E, Nn);

  // Layer 0: [N,128] -> [N,256]
  run_layer(nf, true, IN, 4, W0, al0, ar0, b0, Wt, feat, h1, false, el, er,
            exs, rdenom, row_ptr, esrc, Nn, stream);
  // Layer 1: [N,256] -> [N,256]
  run_layer(h1, false, 256, 4, W1, al1, ar1, b1, Wt, feat, h2, false, el, er,
            exs, rdenom, row_ptr, esrc, Nn, stream);
  // Layer 2: [N,256] -> [N,64]
  run_layer(h2, false, 256, 1, W2, al2, ar2, b2, Wt, feat, d_out, true, el, er,
            exs, rdenom, row_ptr, esrc, Nn, stream);
}

// Round 4
// 360.240 us; speedup vs baseline: 3.6490x; 1.3594x over previous
//
#include <hip/hip_runtime.h>

// ---------------------------------------------------------------------------
// GAT 3-layer forward. bf16 MFMA GEMMs + bf16 feat for the edge gather.
// CSR pull aggregation (no float atomics), CSR built once via parallel
// hierarchical scan, reused 3x. Softmax max-subtraction skipped (bounded
// exponents, fp32 exp safe).
// ---------------------------------------------------------------------------

typedef __attribute__((ext_vector_type(8))) short short8;
typedef __attribute__((ext_vector_type(4))) float f32x4;

__device__ __forceinline__ float bf2f(ushort u) {
  union { unsigned int i; float f; } c;
  c.i = ((unsigned int)u) << 16;
  return c.f;
}
__device__ __forceinline__ ushort f2bf(float f) {
  union { float f; unsigned int i; } c;
  c.f = f;
  unsigned int u = c.i;
  u += 0x7FFFu + ((u >> 16) & 1u);
  return (ushort)(u >> 16);
}

// ------------------------- weight transpose+convert ------------------------
__global__ void convert_w_kernel(const float* __restrict__ W,
                                 ushort* __restrict__ Wt, int K, int N) {
  const int i = blockIdx.x * 256 + threadIdx.x;
  if (i >= K * N) return;
  const int k = i / N, n = i - k * N;
  Wt[n * K + k] = f2bf(W[i]);
}

// ------------------------------ bf16 GEMM ----------------------------------
template <bool AF32>
__global__ __launch_bounds__(256) void gemm_bf16_kernel(
    const void* __restrict__ Ap, const ushort* __restrict__ Wt,
    ushort* __restrict__ C, int M, int K, int Nc) {
  __shared__ ushort As[128][40];
  __shared__ ushort Bs[64][40];
  const int bm = blockIdx.x * 128;
  const int bn = blockIdx.y * 64;
  const int tid = threadIdx.x;
  const int lane = tid & 63;
  const int wave = tid >> 6;
  const int wm = wave >> 1;
  const int wn = wave & 1;
  const int ar = tid >> 1;
  const int ac = (tid & 1) * 16;
  const int brow = tid >> 2;
  const int bk = (tid & 3) * 8;
  const bool a_ok = (bm + ar) < M;

  f32x4 acc[4][2];
#pragma unroll
  for (int m = 0; m < 4; ++m)
#pragma unroll
    for (int n = 0; n < 2; ++n) acc[m][n] = 0.f;

  for (int k0 = 0; k0 < K; k0 += 32) {
    short8 h0, h1;
    if (AF32) {
      const float* A = (const float*)Ap;
      float buf[16];
      if (a_ok) {
        const float* p = A + (size_t)(bm + ar) * K + k0 + ac;
#pragma unroll
        for (int q = 0; q < 4; ++q) {
          float4 v = *(const float4*)(p + q * 4);
          buf[q * 4 + 0] = v.x;
          buf[q * 4 + 1] = v.y;
          buf[q * 4 + 2] = v.z;
          buf[q * 4 + 3] = v.w;
        }
      } else {
#pragma unroll
        for (int q = 0; q < 16; ++q) buf[q] = 0.f;
      }
#pragma unroll
      for (int q = 0; q < 8; ++q) h0[q] = (short)f2bf(buf[q]);
#pragma unroll
      for (int q = 0; q < 8; ++q) h1[q] = (short)f2bf(buf[8 + q]);
    } else {
      const ushort* A = (const ushort*)Ap;
      if (a_ok) {
        const ushort* p = A + (size_t)(bm + ar) * K + k0 + ac;
        h0 = *(const short8*)p;
        h1 = *(const short8*)(p + 8);
      } else {
        h0 = 0;
        h1 = 0;
      }
    }
    *(short8*)&As[ar][ac] = h0;
    *(short8*)&As[ar][ac + 8] = h1;
    *(short8*)&Bs[brow][bk] =
        *(const short8*)(Wt + (size_t)(bn + brow) * K + k0 + bk);
    __syncthreads();

    short8 a[4], b[2];
#pragma unroll
    for (int m = 0; m < 4; ++m)
      a[m] = *(const short8*)&As[wm * 64 + m * 16 + (lane & 15)][(lane >> 4) * 8];
#pragma unroll
    for (int n = 0; n < 2; ++n)
      b[n] = *(const short8*)&Bs[wn * 32 + n * 16 + (lane & 15)][(lane >> 4) * 8];
#pragma unroll
    for (int m = 0; m < 4; ++m)
#pragma unroll
      for (int n = 0; n < 2; ++n)
        acc[m][n] = __builtin_amdgcn_mfma_f32_16x16x32_bf16(a[m], b[n],
                                                            acc[m][n], 0, 0, 0);
    __syncthreads();
  }

#pragma unroll
  for (int m = 0; m < 4; ++m) {
#pragma unroll
    for (int r = 0; r < 4; ++r) {
      const int row = bm + wm * 64 + m * 16 + (lane >> 4) * 4 + r;
      if (row < M) {
#pragma unroll
        for (int n = 0; n < 2; ++n) {
          const int col = bn + wn * 32 + n * 16 + (lane & 15);
          C[(size_t)row * Nc + col] = f2bf(acc[m][n][r]);
        }
      }
    }
  }
}

// --------------------------- attn coefficients -----------------------------
// H=4: one wave per node; lane covers channels 4*lane..4*lane+3 (short4),
// head = lane>>4; reduce within 16-lane group.
__global__ __launch_bounds__(256) void attn_coef_h4(
    const ushort* __restrict__ feat, const float* __restrict__ al,
    const float* __restrict__ ar, float* __restrict__ el,
    float* __restrict__ er, int Nn) {
  const int n = (blockIdx.x * 256 + threadIdx.x) >> 6;
  const int lane = threadIdx.x & 63;
  if (n >= Nn) return;
  const short4 v = ((const short4*)(feat + (size_t)n * 256))[lane];
  const float4 a = ((const float4*)al)[lane];
  const float4 r = ((const float4*)ar)[lane];
  const float f0 = bf2f((ushort)v.x), f1 = bf2f((ushort)v.y),
              f2 = bf2f((ushort)v.z), f3 = bf2f((ushort)v.w);
  float pl = f0 * a.x + f1 * a.y + f2 * a.z + f3 * a.w;
  float pr = f0 * r.x + f1 * r.y + f2 * r.z + f3 * r.w;
#pragma unroll
  for (int off = 1; off < 16; off <<= 1) {
    pl += __shfl_xor(pl, off);
    pr += __shfl_xor(pr, off);
  }
  if ((lane & 15) == 0) {
    el[n * 4 + (lane >> 4)] = pl;
    er[n * 4 + (lane >> 4)] = pr;
  }
}

// H=1: 4 nodes per wave; 16-lane group per node, lane covers 4 channels.
__global__ __launch_bounds__(256) void attn_coef_h1(
    const ushort* __restrict__ feat, const float* __restrict__ al,
    const float* __restrict__ ar, float* __restrict__ el,
    float* __restrict__ er, int Nn) {
  const int wid = (blockIdx.x * 256 + threadIdx.x) >> 6;
  const int lane = threadIdx.x & 63;
  const int n = wid * 4 + (lane >> 4);
  const int sub = lane & 15;
  if (n >= Nn) return;
  const short4 v = ((const short4*)(feat + (size_t)n * 64))[sub];
  const float4 a = ((const float4*)al)[sub];
  const float4 r = ((const float4*)ar)[sub];
  const float f0 = bf2f((ushort)v.x), f1 = bf2f((ushort)v.y),
              f2 = bf2f((ushort)v.z), f3 = bf2f((ushort)v.w);
  float pl = f0 * a.x + f1 * a.y + f2 * a.z + f3 * a.w;
  float pr = f0 * r.x + f1 * r.y + f2 * r.z + f3 * r.w;
#pragma unroll
  for (int off = 1; off < 16; off <<= 1) {
    pl += __shfl_xor(pl, off);
    pr += __shfl_xor(pr, off);
  }
  if (sub == 0) {
    el[n] = pl;
    er[n] = pr;
  }
}

// ------------------------- CSR construction -------------------------------
__global__ void hist_kernel(const int* __restrict__ dst, int* __restrict__ cnt,
                            int E, int Nn) {
  const int e = blockIdx.x * blockDim.x + threadIdx.x;
  if (e >= E + Nn) return;
  const int d = (e < E) ? dst[e] : (e - E);
  atomicAdd(&cnt[d], 1);
}

__device__ __forceinline__ int block_incl_scan_1024(int x, int* lds16) {
  const int lane = threadIdx.x & 63;
  const int wid = threadIdx.x >> 6;
  int inc = x;
#pragma unroll
  for (int off = 1; off < 64; off <<= 1) {
    const int y = __shfl_up(inc, off);
    if (lane >= off) inc += y;
  }
  if (lane == 63) lds16[wid] = inc;
  __syncthreads();
  if (wid == 0) {
    int t = (lane < 16) ? lds16[lane] : 0;
#pragma unroll
    for (int off = 1; off < 16; off <<= 1) {
      const int y = __shfl_up(t, off);
      if (lane >= off) t += y;
    }
    if (lane < 16) lds16[lane] = t;
  }
  __syncthreads();
  if (wid > 0) inc += lds16[wid - 1];
  return inc;
}

// Stage 1: per-block exclusive scan (local), block totals to partials.
__global__ __launch_bounds__(1024) void scan_blocks_kernel(
    const int* __restrict__ cnt, int* __restrict__ row_ptr,
    int* __restrict__ partials, int n) {
  __shared__ int lds16[16];
  const int i = blockIdx.x * 1024 + threadIdx.x;
  const int x = (i < n) ? cnt[i] : 0;
  const int inc = block_incl_scan_1024(x, lds16);
  if (i < n) row_ptr[i] = inc - x;
  if (threadIdx.x == 1023) partials[blockIdx.x] = inc;
}

// Stage 2: single block scans the partials (nb <= 1024), writes grand total.
__global__ __launch_bounds__(1024) void scan_partials_kernel(
    int* __restrict__ partials, int* __restrict__ row_ptr, int nb, int n) {
  __shared__ int lds16[16];
  const int x = (threadIdx.x < nb) ? partials[threadIdx.x] : 0;
  const int inc = block_incl_scan_1024(x, lds16);
  if (threadIdx.x < nb) partials[threadIdx.x] = inc - x;
  if (threadIdx.x == nb - 1) row_ptr[n] = inc;
}

// Stage 3: add block offsets; also init cursor.
__global__ __launch_bounds__(1024) void add_offsets_kernel(
    int* __restrict__ row_ptr, int* __restrict__ cursor,
    const int* __restrict__ partials, int n) {
  const int i = blockIdx.x * 1024 + threadIdx.x;
  if (i < n) {
    const int v = row_ptr[i] + partials[blockIdx.x];
    row_ptr[i] = v;
    cursor[i] = v;
  }
}

__global__ void scatter_kernel(const int* __restrict__ src,
                               const int* __restrict__ dst,
                               int* __restrict__ cursor, int* __restrict__ esrc,
                               int E, int Nn) {
  const int e = blockIdx.x * blockDim.x + threadIdx.x;
  if (e >= E + Nn) return;
  const int s = (e < E) ? src[e] : (e - E);
  const int d = (e < E) ? dst[e] : (e - E);
  const int pos = atomicAdd(&cursor[d], 1);
  esrc[pos] = s;
}

// --------------------- edge softmax (pull, no atomics) --------------------
template <int H>
__global__ __launch_bounds__(256) void edge_softmax_csr(
    const int* __restrict__ row_ptr, const int* __restrict__ esrc,
    const float* __restrict__ el, const float* __restrict__ er,
    float* __restrict__ exs, float* __restrict__ rdenom, int Nn) {
  const int wid = (blockIdx.x * 256 + threadIdx.x) >> 6;
  const int lane = threadIdx.x & 63;
  if (wid >= Nn) return;
  const int n = wid;
  const int start = row_ptr[n];
  const int deg = row_ptr[n + 1] - start;
  const int h = (H == 4) ? (lane & 3) : 0;
  const float erv = er[n * H + h];
  float part = 0.f;
  for (int idx = lane; idx < deg * H; idx += 64) {
    const int i = (H == 4) ? (idx >> 2) : idx;
    const int s = esrc[start + i];
    float x = el[s * H + h] + erv;
    x = (x > 0.f) ? x : 0.2f * x;
    const float v = __expf(x);
    exs[(start + i) * H + h] = v;
    part += v;
  }
  if (H == 4) {
    part += __shfl_xor(part, 4);
    part += __shfl_xor(part, 8);
    part += __shfl_xor(part, 16);
    part += __shfl_xor(part, 32);
    if (lane < 4) rdenom[n * 4 + lane] = 1.f / part;
  } else {
#pragma unroll
    for (int off = 1; off < 64; off <<= 1) part += __shfl_xor(part, off);
    if (lane == 0) rdenom[n] = 1.f / part;
  }
}

// --------------------- aggregation (pull, no atomics) ---------------------
__global__ __launch_bounds__(256) void aggregate_csr_h4(
    const int* __restrict__ row_ptr, const int* __restrict__ esrc,
    const float* __restrict__ exs, const float* __restrict__ rdenom,
    const ushort* __restrict__ feat, const float* __restrict__ b,
    ushort* __restrict__ out, int Nn) {
  const int n = blockIdx.x;
  const int c = threadIdx.x;
  const int h = c >> 6;
  const int start = row_ptr[n];
  const int end = row_ptr[n + 1];
  float acc = 0.f;
  int i = start;
  for (; i + 1 < end; i += 2) {
    const int s0 = esrc[i];
    const int s1 = esrc[i + 1];
    const float v0 = exs[i * 4 + h];
    const float v1 = exs[(i + 1) * 4 + h];
    const float f0 = bf2f(feat[(size_t)s0 * 256 + c]);
    const float f1 = bf2f(feat[(size_t)s1 * 256 + c]);
    acc = fmaf(v0, f0, acc);
    acc = fmaf(v1, f1, acc);
  }
  if (i < end) {
    const int s = esrc[i];
    acc = fmaf(exs[i * 4 + h], bf2f(feat[(size_t)s * 256 + c]), acc);
  }
  out[(size_t)n * 256 + c] = f2bf(acc * rdenom[n * 4 + h] + b[c]);
}

__global__ __launch_bounds__(256) void aggregate_csr_h1(
    const int* __restrict__ row_ptr, const int* __restrict__ esrc,
    const float* __restrict__ exs, const float* __restrict__ rdenom,
    const ushort* __restrict__ feat, const float* __restrict__ b,
    float* __restrict__ out, int Nn) {
  const int wid = (blockIdx.x * 256 + threadIdx.x) >> 6;
  const int lane = threadIdx.x & 63;
  if (wid >= Nn) return;
  const int n = wid;
  const int start = row_ptr[n];
  const int end = row_ptr[n + 1];
  float acc = 0.f;
  int i = start;
  for (; i + 1 < end; i += 2) {
    const int s0 = esrc[i];
    const int s1 = esrc[i + 1];
    const float f0 = bf2f(feat[(size_t)s0 * 64 + lane]);
    const float f1 = bf2f(feat[(size_t)s1 * 64 + lane]);
    acc = fmaf(exs[i], f0, acc);
    acc = fmaf(exs[i + 1], f1, acc);
  }
  if (i < end) acc = fmaf(exs[i], bf2f(feat[(size_t)esrc[i] * 64 + lane]), acc);
  out[(size_t)n * 64 + lane] = acc * rdenom[n] + b[lane];
}

// ------------------------------- driver -----------------------------------
static void run_layer(const void* hin, bool af32, int K, int H, const float* W,
                      const float* al, const float* ar, const float* b,
                      ushort* Wt, ushort* feat, void* out, float* el,
                      float* er, float* exs, float* rdenom,
                      const int* row_ptr, const int* esrc, int Nn,
                      hipStream_t stream) {
  const int HF = H * 64;
  convert_w_kernel<<<(K * HF + 255) / 256, 256, 0, stream>>>(W, Wt, K, HF);
  dim3 gg((Nn + 127) / 128, HF / 64);
  if (af32)
    gemm_bf16_kernel<true><<<gg, 256, 0, stream>>>(hin, Wt, feat, Nn, K, HF);
  else
    gemm_bf16_kernel<false><<<gg, 256, 0, stream>>>(hin, Wt, feat, Nn, K, HF);
  const int waves_grid = (Nn * 64 + 255) / 256;
  if (H == 4) {
    attn_coef_h4<<<waves_grid, 256, 0, stream>>>(feat, al, ar, el, er, Nn);
    edge_softmax_csr<4><<<waves_grid, 256, 0, stream>>>(row_ptr, esrc, el, er,
                                                        exs, rdenom, Nn);
    aggregate_csr_h4<<<Nn, 256, 0, stream>>>(row_ptr, esrc, exs, rdenom, feat,
                                             b, (ushort*)out, Nn);
  } else {
    attn_coef_h1<<<(Nn * 16 + 255) / 256, 256, 0, stream>>>(feat, al, ar, el,
                                                            er, Nn);
    edge_softmax_csr<1><<<waves_grid, 256, 0, stream>>>(row_ptr, esrc, el, er,
                                                        exs, rdenom, Nn);
    aggregate_csr_h1<<<waves_grid, 256, 0, stream>>>(
        row_ptr, esrc, exs, rdenom, feat, b, (float*)out, Nn);
  }
}

extern "C" void kernel_launch(void* const* d_in, const int* in_sizes, int n_in,
                              void* d_out, int out_size, void* d_ws,
                              size_t ws_size, hipStream_t stream) {
  const float* nf = (const float*)d_in[0];
  const int* src = (const int*)d_in[1];
  const int* dst = (const int*)d_in[2];
  const float* W0 = (const float*)d_in[3];
  const float* al0 = (const float*)d_in[4];
  const float* ar0 = (const float*)d_in[5];
  const float* b0 = (const float*)d_in[6];
  const float* W1 = (const float*)d_in[7];
  const float* al1 = (const float*)d_in[8];
  const float* ar1 = (const float*)d_in[9];
  const float* b1 = (const float*)d_in[10];
  const float* W2 = (const float*)d_in[11];
  const float* al2 = (const float*)d_in[12];
  const float* ar2 = (const float*)d_in[13];
  const float* b2 = (const float*)d_in[14];

  const int IN = 128;
  const int Nn = in_sizes[0] / IN;
  const int E = in_sizes[1];
  const int ET = E + Nn;

  char* ws = (char*)d_ws;
  size_t off = 0;
  auto alloc = [&](size_t bytes) {
    char* p = ws + off;
    off += (bytes + 255) & ~(size_t)255;
    return p;
  };
  ushort* feat = (ushort*)alloc((size_t)Nn * 256 * 2);
  ushort* h1 = (ushort*)alloc((size_t)Nn * 256 * 2);
  ushort* h2 = (ushort*)alloc((size_t)Nn * 256 * 2);
  ushort* Wt = (ushort*)alloc((size_t)256 * 256 * 2);
  float* el = (float*)alloc((size_t)Nn * 4 * 4);
  float* er = (float*)alloc((size_t)Nn * 4 * 4);
  float* rdenom = (float*)alloc((size_t)Nn * 4 * 4);
  float* exs = (float*)alloc((size_t)ET * 4 * 4);
  int* row_ptr = (int*)alloc(((size_t)Nn + 1) * 4);
  int* cnt = (int*)alloc((size_t)Nn * 4);
  int* cursor = (int*)alloc((size_t)Nn * 4);
  int* esrc = (int*)alloc((size_t)ET * 4);
  int* partials = (int*)alloc((size_t)1024 * 4);
  (void)ws_size;
  (void)n_in;
  (void)out_size;

  // ---- Build CSR over dst (reused by all 3 layers) ----
  const int nb = (Nn + 1023) / 1024;
  hipMemsetAsync(cnt, 0, (size_t)Nn * sizeof(int), stream);
  hist_kernel<<<(ET + 255) / 256, 256, 0, stream>>>(dst, cnt, E, Nn);
  scan_blocks_kernel<<<nb, 1024, 0, stream>>>(cnt, row_ptr, partials, Nn);
  scan_partials_kernel<<<1, 1024, 0, stream>>>(partials, row_ptr, nb, Nn);
  add_offsets_kernel<<<nb, 1024, 0, stream>>>(row_ptr, cursor, partials, Nn);
  scatter_kernel<<<(ET + 255) / 256, 256, 0, stream>>>(src, dst, cursor, esrc,
                                                       E, Nn);

  // Layer 0: [N,128] -> [N,256]
  run_layer(nf, true, IN, 4, W0, al0, ar0, b0, Wt, feat, h1, el, er, exs,
            rdenom, row_ptr, esrc, Nn, stream);
  // Layer 1: [N,256] -> [N,256]
  run_layer(h1, false, 256, 4, W1, al1, ar1, b1, Wt, feat, h2, el, er, exs,
            rdenom, row_ptr, esrc, Nn, stream);
  // Layer 2: [N,256] -> [N,64]
  run_layer(h2, false, 256, 1, W2, al2, ar2, b2, Wt, feat, d_out, el, er, exs,
            rdenom, row_ptr, esrc, Nn, stream);
}

// Round 5
// 247.411 us; speedup vs baseline: 5.3130x; 1.4560x over previous
//
#include <hip/hip_runtime.h>

// ---------------------------------------------------------------------------
// GAT 3-layer forward. bf16 MFMA GEMMs + bf16 feat edge gather.
// CSR pull aggregation with FUSED edge-softmax: per dest node accumulate
// den = sum ex_i and acc = sum ex_i*feat[src_i] in one pass; out = acc/den+b.
// No exs buffer, no float atomics. CSR built once (parallel scan), reused 3x.
// Softmax max-subtraction skipped (bounded exponents, fp32 exp safe).
// ---------------------------------------------------------------------------

typedef __attribute__((ext_vector_type(8))) short short8;
typedef __attribute__((ext_vector_type(4))) float f32x4;

__device__ __forceinline__ float bf2f(ushort u) {
  union { unsigned int i; float f; } c;
  c.i = ((unsigned int)u) << 16;
  return c.f;
}
__device__ __forceinline__ ushort f2bf(float f) {
  union { float f; unsigned int i; } c;
  c.f = f;
  unsigned int u = c.i;
  u += 0x7FFFu + ((u >> 16) & 1u);
  return (ushort)(u >> 16);
}
__device__ __forceinline__ float lrelu_exp(float x) {
  const float y = (x > 0.f) ? x : 0.2f * x;
  return __expf(y);
}

// ------------------------- weight transpose+convert ------------------------
__global__ void convert_w_kernel(const float* __restrict__ W,
                                 ushort* __restrict__ Wt, int K, int N) {
  const int i = blockIdx.x * 256 + threadIdx.x;
  if (i >= K * N) return;
  const int k = i / N, n = i - k * N;
  Wt[n * K + k] = f2bf(W[i]);
}

// ------------------------------ bf16 GEMM ----------------------------------
template <bool AF32>
__global__ __launch_bounds__(256) void gemm_bf16_kernel(
    const void* __restrict__ Ap, const ushort* __restrict__ Wt,
    ushort* __restrict__ C, int M, int K, int Nc) {
  __shared__ ushort As[128][40];
  __shared__ ushort Bs[64][40];
  const int bm = blockIdx.x * 128;
  const int bn = blockIdx.y * 64;
  const int tid = threadIdx.x;
  const int lane = tid & 63;
  const int wave = tid >> 6;
  const int wm = wave >> 1;
  const int wn = wave & 1;
  const int ar = tid >> 1;
  const int ac = (tid & 1) * 16;
  const int brow = tid >> 2;
  const int bk = (tid & 3) * 8;
  const bool a_ok = (bm + ar) < M;

  f32x4 acc[4][2];
#pragma unroll
  for (int m = 0; m < 4; ++m)
#pragma unroll
    for (int n = 0; n < 2; ++n) acc[m][n] = 0.f;

  for (int k0 = 0; k0 < K; k0 += 32) {
    short8 h0, h1;
    if (AF32) {
      const float* A = (const float*)Ap;
      float buf[16];
      if (a_ok) {
        const float* p = A + (size_t)(bm + ar) * K + k0 + ac;
#pragma unroll
        for (int q = 0; q < 4; ++q) {
          float4 v = *(const float4*)(p + q * 4);
          buf[q * 4 + 0] = v.x;
          buf[q * 4 + 1] = v.y;
          buf[q * 4 + 2] = v.z;
          buf[q * 4 + 3] = v.w;
        }
      } else {
#pragma unroll
        for (int q = 0; q < 16; ++q) buf[q] = 0.f;
      }
#pragma unroll
      for (int q = 0; q < 8; ++q) h0[q] = (short)f2bf(buf[q]);
#pragma unroll
      for (int q = 0; q < 8; ++q) h1[q] = (short)f2bf(buf[8 + q]);
    } else {
      const ushort* A = (const ushort*)Ap;
      if (a_ok) {
        const ushort* p = A + (size_t)(bm + ar) * K + k0 + ac;
        h0 = *(const short8*)p;
        h1 = *(const short8*)(p + 8);
      } else {
        h0 = 0;
        h1 = 0;
      }
    }
    *(short8*)&As[ar][ac] = h0;
    *(short8*)&As[ar][ac + 8] = h1;
    *(short8*)&Bs[brow][bk] =
        *(const short8*)(Wt + (size_t)(bn + brow) * K + k0 + bk);
    __syncthreads();

    short8 a[4], b[2];
#pragma unroll
    for (int m = 0; m < 4; ++m)
      a[m] = *(const short8*)&As[wm * 64 + m * 16 + (lane & 15)][(lane >> 4) * 8];
#pragma unroll
    for (int n = 0; n < 2; ++n)
      b[n] = *(const short8*)&Bs[wn * 32 + n * 16 + (lane & 15)][(lane >> 4) * 8];
#pragma unroll
    for (int m = 0; m < 4; ++m)
#pragma unroll
      for (int n = 0; n < 2; ++n)
        acc[m][n] = __builtin_amdgcn_mfma_f32_16x16x32_bf16(a[m], b[n],
                                                            acc[m][n], 0, 0, 0);
    __syncthreads();
  }

#pragma unroll
  for (int m = 0; m < 4; ++m) {
#pragma unroll
    for (int r = 0; r < 4; ++r) {
      const int row = bm + wm * 64 + m * 16 + (lane >> 4) * 4 + r;
      if (row < M) {
#pragma unroll
        for (int n = 0; n < 2; ++n) {
          const int col = bn + wn * 32 + n * 16 + (lane & 15);
          C[(size_t)row * Nc + col] = f2bf(acc[m][n][r]);
        }
      }
    }
  }
}

// --------------------------- attn coefficients -----------------------------
__global__ __launch_bounds__(256) void attn_coef_h4(
    const ushort* __restrict__ feat, const float* __restrict__ al,
    const float* __restrict__ ar, float* __restrict__ el,
    float* __restrict__ er, int Nn) {
  const int n = (blockIdx.x * 256 + threadIdx.x) >> 6;
  const int lane = threadIdx.x & 63;
  if (n >= Nn) return;
  const short4 v = ((const short4*)(feat + (size_t)n * 256))[lane];
  const float4 a = ((const float4*)al)[lane];
  const float4 r = ((const float4*)ar)[lane];
  const float f0 = bf2f((ushort)v.x), f1 = bf2f((ushort)v.y),
              f2 = bf2f((ushort)v.z), f3 = bf2f((ushort)v.w);
  float pl = f0 * a.x + f1 * a.y + f2 * a.z + f3 * a.w;
  float pr = f0 * r.x + f1 * r.y + f2 * r.z + f3 * r.w;
#pragma unroll
  for (int off = 1; off < 16; off <<= 1) {
    pl += __shfl_xor(pl, off);
    pr += __shfl_xor(pr, off);
  }
  if ((lane & 15) == 0) {
    el[n * 4 + (lane >> 4)] = pl;
    er[n * 4 + (lane >> 4)] = pr;
  }
}

__global__ __launch_bounds__(256) void attn_coef_h1(
    const ushort* __restrict__ feat, const float* __restrict__ al,
    const float* __restrict__ ar, float* __restrict__ el,
    float* __restrict__ er, int Nn) {
  const int wid = (blockIdx.x * 256 + threadIdx.x) >> 6;
  const int lane = threadIdx.x & 63;
  const int n = wid * 4 + (lane >> 4);
  const int sub = lane & 15;
  if (n >= Nn) return;
  const short4 v = ((const short4*)(feat + (size_t)n * 64))[sub];
  const float4 a = ((const float4*)al)[sub];
  const float4 r = ((const float4*)ar)[sub];
  const float f0 = bf2f((ushort)v.x), f1 = bf2f((ushort)v.y),
              f2 = bf2f((ushort)v.z), f3 = bf2f((ushort)v.w);
  float pl = f0 * a.x + f1 * a.y + f2 * a.z + f3 * a.w;
  float pr = f0 * r.x + f1 * r.y + f2 * r.z + f3 * r.w;
#pragma unroll
  for (int off = 1; off < 16; off <<= 1) {
    pl += __shfl_xor(pl, off);
    pr += __shfl_xor(pr, off);
  }
  if (sub == 0) {
    el[n] = pl;
    er[n] = pr;
  }
}

// ------------------------- CSR construction -------------------------------
__global__ void hist_kernel(const int* __restrict__ dst, int* __restrict__ cnt,
                            int E, int Nn) {
  const int e = blockIdx.x * blockDim.x + threadIdx.x;
  if (e >= E + Nn) return;
  const int d = (e < E) ? dst[e] : (e - E);
  atomicAdd(&cnt[d], 1);
}

__device__ __forceinline__ int block_incl_scan_1024(int x, int* lds16) {
  const int lane = threadIdx.x & 63;
  const int wid = threadIdx.x >> 6;
  int inc = x;
#pragma unroll
  for (int off = 1; off < 64; off <<= 1) {
    const int y = __shfl_up(inc, off);
    if (lane >= off) inc += y;
  }
  if (lane == 63) lds16[wid] = inc;
  __syncthreads();
  if (wid == 0) {
    int t = (lane < 16) ? lds16[lane] : 0;
#pragma unroll
    for (int off = 1; off < 16; off <<= 1) {
      const int y = __shfl_up(t, off);
      if (lane >= off) t += y;
    }
    if (lane < 16) lds16[lane] = t;
  }
  __syncthreads();
  if (wid > 0) inc += lds16[wid - 1];
  return inc;
}

__global__ __launch_bounds__(1024) void scan_blocks_kernel(
    const int* __restrict__ cnt, int* __restrict__ row_ptr,
    int* __restrict__ partials, int n) {
  __shared__ int lds16[16];
  const int i = blockIdx.x * 1024 + threadIdx.x;
  const int x = (i < n) ? cnt[i] : 0;
  const int inc = block_incl_scan_1024(x, lds16);
  if (i < n) row_ptr[i] = inc - x;
  if (threadIdx.x == 1023) partials[blockIdx.x] = inc;
}

__global__ __launch_bounds__(1024) void scan_partials_kernel(
    int* __restrict__ partials, int* __restrict__ row_ptr, int nb, int n) {
  __shared__ int lds16[16];
  const int x = (threadIdx.x < nb) ? partials[threadIdx.x] : 0;
  const int inc = block_incl_scan_1024(x, lds16);
  if (threadIdx.x < nb) partials[threadIdx.x] = inc - x;
  if (threadIdx.x == nb - 1) row_ptr[n] = inc;
}

__global__ __launch_bounds__(1024) void add_offsets_kernel(
    int* __restrict__ row_ptr, int* __restrict__ cursor,
    const int* __restrict__ partials, int n) {
  const int i = blockIdx.x * 1024 + threadIdx.x;
  if (i < n) {
    const int v = row_ptr[i] + partials[blockIdx.x];
    row_ptr[i] = v;
    cursor[i] = v;
  }
}

__global__ void scatter_kernel(const int* __restrict__ src,
                               const int* __restrict__ dst,
                               int* __restrict__ cursor, int* __restrict__ esrc,
                               int E, int Nn) {
  const int e = blockIdx.x * blockDim.x + threadIdx.x;
  if (e >= E + Nn) return;
  const int s = (e < E) ? src[e] : (e - E);
  const int d = (e < E) ? dst[e] : (e - E);
  const int pos = atomicAdd(&cursor[d], 1);
  esrc[pos] = s;
}

// --------------- FUSED softmax + aggregation (pull, no atomics) -----------
// H=4: one wave per node. Lane owns channels 4*lane..4*lane+3 (short4),
// head h = lane>>4. den is accumulated redundantly per lane (no shuffles).
__global__ __launch_bounds__(256) void agg_fused_h4(
    const int* __restrict__ row_ptr, const int* __restrict__ esrc,
    const float* __restrict__ el, const float* __restrict__ er,
    const ushort* __restrict__ feat, const float* __restrict__ b,
    ushort* __restrict__ out, int Nn) {
  const int n = (blockIdx.x * 256 + threadIdx.x) >> 6;
  const int lane = threadIdx.x & 63;
  if (n >= Nn) return;
  const int h = lane >> 4;
  const int start = row_ptr[n];
  const int end = row_ptr[n + 1];
  const float erv = er[n * 4 + h];
  const short4* feat4 = (const short4*)feat;

  float den = 0.f;
  f32x4 acc = 0.f;
  int i = start;
  for (; i + 3 < end; i += 4) {
    const int s0 = esrc[i], s1 = esrc[i + 1], s2 = esrc[i + 2],
              s3 = esrc[i + 3];
    const float x0 = el[s0 * 4 + h] + erv;
    const float x1 = el[s1 * 4 + h] + erv;
    const float x2 = el[s2 * 4 + h] + erv;
    const float x3 = el[s3 * 4 + h] + erv;
    const short4 f0 = feat4[(size_t)s0 * 64 + lane];
    const short4 f1 = feat4[(size_t)s1 * 64 + lane];
    const short4 f2 = feat4[(size_t)s2 * 64 + lane];
    const short4 f3 = feat4[(size_t)s3 * 64 + lane];
    const float e0 = lrelu_exp(x0), e1 = lrelu_exp(x1), e2 = lrelu_exp(x2),
                e3 = lrelu_exp(x3);
    den += (e0 + e1) + (e2 + e3);
    acc[0] += e0 * bf2f((ushort)f0.x) + e1 * bf2f((ushort)f1.x) +
              e2 * bf2f((ushort)f2.x) + e3 * bf2f((ushort)f3.x);
    acc[1] += e0 * bf2f((ushort)f0.y) + e1 * bf2f((ushort)f1.y) +
              e2 * bf2f((ushort)f2.y) + e3 * bf2f((ushort)f3.y);
    acc[2] += e0 * bf2f((ushort)f0.z) + e1 * bf2f((ushort)f1.z) +
              e2 * bf2f((ushort)f2.z) + e3 * bf2f((ushort)f3.z);
    acc[3] += e0 * bf2f((ushort)f0.w) + e1 * bf2f((ushort)f1.w) +
              e2 * bf2f((ushort)f2.w) + e3 * bf2f((ushort)f3.w);
  }
  for (; i < end; ++i) {
    const int s = esrc[i];
    const float ex = lrelu_exp(el[s * 4 + h] + erv);
    const short4 f = feat4[(size_t)s * 64 + lane];
    den += ex;
    acc[0] += ex * bf2f((ushort)f.x);
    acc[1] += ex * bf2f((ushort)f.y);
    acc[2] += ex * bf2f((ushort)f.z);
    acc[3] += ex * bf2f((ushort)f.w);
  }
  const float rden = 1.f / den;
  const float4 bb = ((const float4*)b)[lane];
  short4 o;
  o.x = (short)f2bf(acc[0] * rden + bb.x);
  o.y = (short)f2bf(acc[1] * rden + bb.y);
  o.z = (short)f2bf(acc[2] * rden + bb.z);
  o.w = (short)f2bf(acc[3] * rden + bb.w);
  ((short4*)out)[(size_t)n * 64 + lane] = o;
}

// H=1: one wave per node; lane owns 1 channel of 64. fp32 output.
__global__ __launch_bounds__(256) void agg_fused_h1(
    const int* __restrict__ row_ptr, const int* __restrict__ esrc,
    const float* __restrict__ el, const float* __restrict__ er,
    const ushort* __restrict__ feat, const float* __restrict__ b,
    float* __restrict__ out, int Nn) {
  const int n = (blockIdx.x * 256 + threadIdx.x) >> 6;
  const int lane = threadIdx.x & 63;
  if (n >= Nn) return;
  const int start = row_ptr[n];
  const int end = row_ptr[n + 1];
  const float erv = er[n];

  float den = 0.f;
  float acc = 0.f;
  int i = start;
  for (; i + 3 < end; i += 4) {
    const int s0 = esrc[i], s1 = esrc[i + 1], s2 = esrc[i + 2],
              s3 = esrc[i + 3];
    const float x0 = el[s0] + erv, x1 = el[s1] + erv, x2 = el[s2] + erv,
                x3 = el[s3] + erv;
    const ushort f0 = feat[(size_t)s0 * 64 + lane];
    const ushort f1 = feat[(size_t)s1 * 64 + lane];
    const ushort f2 = feat[(size_t)s2 * 64 + lane];
    const ushort f3 = feat[(size_t)s3 * 64 + lane];
    const float e0 = lrelu_exp(x0), e1 = lrelu_exp(x1), e2 = lrelu_exp(x2),
                e3 = lrelu_exp(x3);
    den += (e0 + e1) + (e2 + e3);
    acc += e0 * bf2f(f0) + e1 * bf2f(f1) + e2 * bf2f(f2) + e3 * bf2f(f3);
  }
  for (; i < end; ++i) {
    const int s = esrc[i];
    const float ex = lrelu_exp(el[s] + erv);
    den += ex;
    acc += ex * bf2f(feat[(size_t)s * 64 + lane]);
  }
  out[(size_t)n * 64 + lane] = acc * (1.f / den) + b[lane];
}

// ------------------------------- driver -----------------------------------
static void run_layer(const void* hin, bool af32, int K, int H, const float* W,
                      const float* al, const float* ar, const float* b,
                      ushort* Wt, ushort* feat, void* out, float* el,
                      float* er, const int* row_ptr, const int* esrc, int Nn,
                      hipStream_t stream) {
  const int HF = H * 64;
  convert_w_kernel<<<(K * HF + 255) / 256, 256, 0, stream>>>(W, Wt, K, HF);
  dim3 gg((Nn + 127) / 128, HF / 64);
  if (af32)
    gemm_bf16_kernel<true><<<gg, 256, 0, stream>>>(hin, Wt, feat, Nn, K, HF);
  else
    gemm_bf16_kernel<false><<<gg, 256, 0, stream>>>(hin, Wt, feat, Nn, K, HF);
  const int waves_grid = (Nn * 64 + 255) / 256;
  if (H == 4) {
    attn_coef_h4<<<waves_grid, 256, 0, stream>>>(feat, al, ar, el, er, Nn);
    agg_fused_h4<<<waves_grid, 256, 0, stream>>>(row_ptr, esrc, el, er, feat,
                                                 b, (ushort*)out, Nn);
  } else {
    attn_coef_h1<<<(Nn * 16 + 255) / 256, 256, 0, stream>>>(feat, al, ar, el,
                                                            er, Nn);
    agg_fused_h1<<<waves_grid, 256, 0, stream>>>(row_ptr, esrc, el, er, feat,
                                                 b, (float*)out, Nn);
  }
}

extern "C" void kernel_launch(void* const* d_in, const int* in_sizes, int n_in,
                              void* d_out, int out_size, void* d_ws,
                              size_t ws_size, hipStream_t stream) {
  const float* nf = (const float*)d_in[0];
  const int* src = (const int*)d_in[1];
  const int* dst = (const int*)d_in[2];
  const float* W0 = (const float*)d_in[3];
  const float* al0 = (const float*)d_in[4];
  const float* ar0 = (const float*)d_in[5];
  const float* b0 = (const float*)d_in[6];
  const float* W1 = (const float*)d_in[7];
  const float* al1 = (const float*)d_in[8];
  const float* ar1 = (const float*)d_in[9];
  const float* b1 = (const float*)d_in[10];
  const float* W2 = (const float*)d_in[11];
  const float* al2 = (const float*)d_in[12];
  const float* ar2 = (const float*)d_in[13];
  const float* b2 = (const float*)d_in[14];

  const int IN = 128;
  const int Nn = in_sizes[0] / IN;
  const int E = in_sizes[1];
  const int ET = E + Nn;

  char* ws = (char*)d_ws;
  size_t off = 0;
  auto alloc = [&](size_t bytes) {
    char* p = ws + off;
    off += (bytes + 255) & ~(size_t)255;
    return p;
  };
  ushort* feat = (ushort*)alloc((size_t)Nn * 256 * 2);
  ushort* h1 = (ushort*)alloc((size_t)Nn * 256 * 2);
  ushort* h2 = (ushort*)alloc((size_t)Nn * 256 * 2);
  ushort* Wt = (ushort*)alloc((size_t)256 * 256 * 2);
  float* el = (float*)alloc((size_t)Nn * 4 * 4);
  float* er = (float*)alloc((size_t)Nn * 4 * 4);
  int* row_ptr = (int*)alloc(((size_t)Nn + 1) * 4);
  int* cnt = (int*)alloc((size_t)Nn * 4);
  int* cursor = (int*)alloc((size_t)Nn * 4);
  int* esrc = (int*)alloc((size_t)ET * 4);
  int* partials = (int*)alloc((size_t)1024 * 4);
  (void)ws_size;
  (void)n_in;
  (void)out_size;

  // ---- Build CSR over dst (reused by all 3 layers) ----
  const int nb = (Nn + 1023) / 1024;
  hipMemsetAsync(cnt, 0, (size_t)Nn * sizeof(int), stream);
  hist_kernel<<<(ET + 255) / 256, 256, 0, stream>>>(dst, cnt, E, Nn);
  scan_blocks_kernel<<<nb, 1024, 0, stream>>>(cnt, row_ptr, partials, Nn);
  scan_partials_kernel<<<1, 1024, 0, stream>>>(partials, row_ptr, nb, Nn);
  add_offsets_kernel<<<nb, 1024, 0, stream>>>(row_ptr, cursor, partials, Nn);
  scatter_kernel<<<(ET + 255) / 256, 256, 0, stream>>>(src, dst, cursor, esrc,
                                                       E, Nn);

  // Layer 0: [N,128] -> [N,256]
  run_layer(nf, true, IN, 4, W0, al0, ar0, b0, Wt, feat, h1, el, er, row_ptr,
            esrc, Nn, stream);
  // Layer 1: [N,256] -> [N,256]
  run_layer(h1, false, 256, 4, W1, al1, ar1, b1, Wt, feat, h2, el, er,
            row_ptr, esrc, Nn, stream);
  // Layer 2: [N,256] -> [N,64]
  run_layer(h2, false, 256, 1, W2, al2, ar2, b2, Wt, feat, d_out, el, er,
            row_ptr, esrc, Nn, stream);
}

// Round 6
// 235.874 us; speedup vs baseline: 5.5729x; 1.0489x over previous
//
#include <hip/hip_runtime.h>

// ---------------------------------------------------------------------------
// GAT 3-layer forward. bf16 MFMA GEMMs (m97-style global_load_lds staging) +
// bf16 feat edge gather. CSR pull aggregation with fused edge-softmax, edge
// lists padded to x4 with sentinel edges (src=Nn, el=-1e9 -> exp=+0) so the
// agg loop is uniform 4-unrolled with no tail. No float atomics anywhere.
// Softmax max-subtraction skipped (bounded exponents, fp32 exp safe).
// ---------------------------------------------------------------------------

typedef __attribute__((ext_vector_type(8))) short short8;
typedef __attribute__((ext_vector_type(4))) float f32x4;

__device__ __forceinline__ float bf2f(ushort u) {
  union { unsigned int i; float f; } c;
  c.i = ((unsigned int)u) << 16;
  return c.f;
}
__device__ __forceinline__ ushort f2bf(float f) {
  union { float f; unsigned int i; } c;
  c.f = f;
  unsigned int u = c.i;
  u += 0x7FFFu + ((u >> 16) & 1u);
  return (ushort)(u >> 16);
}
__device__ __forceinline__ float lrelu_exp(float x) {
  const float y = fmaxf(x, 0.2f * x);  // leaky_relu via max (x>0 -> x)
  return __expf(y);
}
__device__ __forceinline__ void gload_lds16(const ushort* g, void* lds) {
  __builtin_amdgcn_global_load_lds(
      (const __attribute__((address_space(1))) unsigned int*)g,
      (__attribute__((address_space(3))) unsigned int*)lds, 16, 0, 0);
}

// ---------------------- input fp32 -> bf16 convert -------------------------
__global__ __launch_bounds__(256) void cvt_f32_bf16(const float* __restrict__ in,
                                                    ushort* __restrict__ out,
                                                    int n8) {
  const int i = blockIdx.x * 256 + threadIdx.x;
  if (i >= n8) return;
  const float4 v0 = ((const float4*)in)[i * 2];
  const float4 v1 = ((const float4*)in)[i * 2 + 1];
  short8 o;
  o[0] = (short)f2bf(v0.x); o[1] = (short)f2bf(v0.y);
  o[2] = (short)f2bf(v0.z); o[3] = (short)f2bf(v0.w);
  o[4] = (short)f2bf(v1.x); o[5] = (short)f2bf(v1.y);
  o[6] = (short)f2bf(v1.z); o[7] = (short)f2bf(v1.w);
  ((short8*)out)[i] = o;
}

// ------------------------- weight transpose+convert ------------------------
// W fp32 [K][N] -> Wt bf16 [N][K]
__global__ void convert_w_kernel(const float* __restrict__ W,
                                 ushort* __restrict__ Wt, int K, int N) {
  const int i = blockIdx.x * 256 + threadIdx.x;
  if (i >= K * N) return;
  const int k = i / N, n = i - k * N;
  Wt[n * K + k] = f2bf(W[i]);
}

// ------------------------------ bf16 GEMM ----------------------------------
// A [M][K] bf16, Wt [Nc][K] bf16 -> C [M][Nc] bf16.
// BM=128, BN template (128 or 64), BK=32; 256 thr = 4 waves (2x2).
// global_load_lds width-16 staging into linear LDS (m97 structure).
template <int BN>
__global__ __launch_bounds__(256) void gemm_mfma(
    const ushort* __restrict__ A, const ushort* __restrict__ Wt,
    ushort* __restrict__ C, int M, int K, int Nc) {
  constexpr int NF = BN / 32;  // n-frags per wave
  __shared__ ushort As[128][32];
  __shared__ ushort Bs[BN][32];
  const int bm = blockIdx.x * 128;
  const int bn = blockIdx.y * BN;
  const int tid = threadIdx.x;
  const int lane = tid & 63;
  const int wave = tid >> 6;
  const int wm = wave >> 1;
  const int wn = wave & 1;

  f32x4 acc[4][NF];
#pragma unroll
  for (int m = 0; m < 4; ++m)
#pragma unroll
    for (int n = 0; n < NF; ++n) acc[m][n] = 0.f;

  for (int k0 = 0; k0 < K; k0 += 32) {
    // stage A: 8 KB = 8 chunks of 1KB (16 rows x 64B); wave w -> chunks w,w+4
#pragma unroll
    for (int c = wave; c < 8; c += 4) {
      const int row = c * 16 + (lane >> 2);
      int rg = bm + row;
      if (rg >= M) rg = M - 1;
      gload_lds16(A + (size_t)rg * K + k0 + (lane & 3) * 8,
                  (char*)(&As[0][0]) + c * 1024);
    }
    // stage B: BN*64 bytes
#pragma unroll
    for (int c = wave; c < BN / 16; c += 4) {
      const int row = c * 16 + (lane >> 2);
      gload_lds16(Wt + (size_t)(bn + row) * K + k0 + (lane & 3) * 8,
                  (char*)(&Bs[0][0]) + c * 1024);
    }
    __syncthreads();  // compiler drains vmcnt before barrier

    short8 a[4], b[NF];
#pragma unroll
    for (int m = 0; m < 4; ++m)
      a[m] = *(const short8*)&As[wm * 64 + m * 16 + (lane & 15)][(lane >> 4) * 8];
#pragma unroll
    for (int n = 0; n < NF; ++n)
      b[n] = *(const short8*)&Bs[wn * (NF * 16) + n * 16 + (lane & 15)]
                             [(lane >> 4) * 8];
#pragma unroll
    for (int m = 0; m < 4; ++m)
#pragma unroll
      for (int n = 0; n < NF; ++n)
        acc[m][n] = __builtin_amdgcn_mfma_f32_16x16x32_bf16(a[m], b[n],
                                                            acc[m][n], 0, 0, 0);
    __syncthreads();
  }

#pragma unroll
  for (int m = 0; m < 4; ++m) {
#pragma unroll
    for (int r = 0; r < 4; ++r) {
      const int row = bm + wm * 64 + m * 16 + (lane >> 4) * 4 + r;
      if (row < M) {
#pragma unroll
        for (int n = 0; n < NF; ++n) {
          const int col = bn + wn * (NF * 16) + n * 16 + (lane & 15);
          C[(size_t)row * Nc + col] = f2bf(acc[m][n][r]);
        }
      }
    }
  }
}

// --------------------------- attn coefficients -----------------------------
__global__ __launch_bounds__(256) void attn_coef_h4(
    const ushort* __restrict__ feat, const float* __restrict__ al,
    const float* __restrict__ ar, float* __restrict__ el,
    float* __restrict__ er, int Nn) {
  if (blockIdx.x == 0 && threadIdx.x < 4) el[Nn * 4 + threadIdx.x] = -1e9f;
  const int n = (blockIdx.x * 256 + threadIdx.x) >> 6;
  const int lane = threadIdx.x & 63;
  if (n >= Nn) return;
  const short4 v = ((const short4*)(feat + (size_t)n * 256))[lane];
  const float4 a = ((const float4*)al)[lane];
  const float4 r = ((const float4*)ar)[lane];
  const float f0 = bf2f((ushort)v.x), f1 = bf2f((ushort)v.y),
              f2 = bf2f((ushort)v.z), f3 = bf2f((ushort)v.w);
  float pl = f0 * a.x + f1 * a.y + f2 * a.z + f3 * a.w;
  float pr = f0 * r.x + f1 * r.y + f2 * r.z + f3 * r.w;
#pragma unroll
  for (int off = 1; off < 16; off <<= 1) {
    pl += __shfl_xor(pl, off);
    pr += __shfl_xor(pr, off);
  }
  if ((lane & 15) == 0) {
    el[n * 4 + (lane >> 4)] = pl;
    er[n * 4 + (lane >> 4)] = pr;
  }
}

__global__ __launch_bounds__(256) void attn_coef_h1(
    const ushort* __restrict__ feat, const float* __restrict__ al,
    const float* __restrict__ ar, float* __restrict__ el,
    float* __restrict__ er, int Nn) {
  if (blockIdx.x == 0 && threadIdx.x == 0) el[Nn] = -1e9f;
  const int wid = (blockIdx.x * 256 + threadIdx.x) >> 6;
  const int lane = threadIdx.x & 63;
  const int n = wid * 4 + (lane >> 4);
  const int sub = lane & 15;
  if (n >= Nn) return;
  const short4 v = ((const short4*)(feat + (size_t)n * 64))[sub];
  const float4 a = ((const float4*)al)[sub];
  const float4 r = ((const float4*)ar)[sub];
  const float f0 = bf2f((ushort)v.x), f1 = bf2f((ushort)v.y),
              f2 = bf2f((ushort)v.z), f3 = bf2f((ushort)v.w);
  float pl = f0 * a.x + f1 * a.y + f2 * a.z + f3 * a.w;
  float pr = f0 * r.x + f1 * r.y + f2 * r.z + f3 * r.w;
#pragma unroll
  for (int off = 1; off < 16; off <<= 1) {
    pl += __shfl_xor(pl, off);
    pr += __shfl_xor(pr, off);
  }
  if (sub == 0) {
    el[n] = pl;
    er[n] = pr;
  }
}

// ------------------------- CSR construction (padded x4) --------------------
__global__ void hist_kernel(const int* __restrict__ dst, int* __restrict__ cnt,
                            int E, int Nn) {
  const int e = blockIdx.x * blockDim.x + threadIdx.x;
  if (e >= E + Nn) return;
  const int d = (e < E) ? dst[e] : (e - E);
  atomicAdd(&cnt[d], 1);
}

__device__ __forceinline__ int block_incl_scan_1024(int x, int* lds16) {
  const int lane = threadIdx.x & 63;
  const int wid = threadIdx.x >> 6;
  int inc = x;
#pragma unroll
  for (int off = 1; off < 64; off <<= 1) {
    const int y = __shfl_up(inc, off);
    if (lane >= off) inc += y;
  }
  if (lane == 63) lds16[wid] = inc;
  __syncthreads();
  if (wid == 0) {
    int t = (lane < 16) ? lds16[lane] : 0;
#pragma unroll
    for (int off = 1; off < 16; off <<= 1) {
      const int y = __shfl_up(t, off);
      if (lane >= off) t += y;
    }
    if (lane < 16) lds16[lane] = t;
  }
  __syncthreads();
  if (wid > 0) inc += lds16[wid - 1];
  return inc;
}

// scans PADDED counts ((cnt+3)&~3)
__global__ __launch_bounds__(1024) void scan_blocks_kernel(
    const int* __restrict__ cnt, int* __restrict__ row_ptr,
    int* __restrict__ partials, int n) {
  __shared__ int lds16[16];
  const int i = blockIdx.x * 1024 + threadIdx.x;
  const int x = (i < n) ? ((cnt[i] + 3) & ~3) : 0;
  const int inc = block_incl_scan_1024(x, lds16);
  if (i < n) row_ptr[i] = inc - x;
  if (threadIdx.x == 1023) partials[blockIdx.x] = inc;
}

__global__ __launch_bounds__(1024) void scan_partials_kernel(
    int* __restrict__ partials, int* __restrict__ row_ptr, int nb, int n) {
  __shared__ int lds16[16];
  const int x = (threadIdx.x < nb) ? partials[threadIdx.x] : 0;
  const int inc = block_incl_scan_1024(x, lds16);
  if (threadIdx.x < nb) partials[threadIdx.x] = inc - x;
  if (threadIdx.x == nb - 1) row_ptr[n] = inc;
}

__global__ __launch_bounds__(1024) void add_offsets_kernel(
    int* __restrict__ row_ptr, int* __restrict__ cursor,
    const int* __restrict__ partials, int n) {
  const int i = blockIdx.x * 1024 + threadIdx.x;
  if (i < n) {
    const int v = row_ptr[i] + partials[blockIdx.x];
    row_ptr[i] = v;
    cursor[i] = v;
  }
}

__global__ void scatter_kernel(const int* __restrict__ src,
                               const int* __restrict__ dst,
                               int* __restrict__ cursor, int* __restrict__ esrc,
                               int E, int Nn) {
  const int e = blockIdx.x * blockDim.x + threadIdx.x;
  if (e >= E + Nn) return;
  const int s = (e < E) ? src[e] : (e - E);
  const int d = (e < E) ? dst[e] : (e - E);
  const int pos = atomicAdd(&cursor[d], 1);
  esrc[pos] = s;
}

// fill padding slots with sentinel src = Nn (el[Nn]=-1e9 -> weight 0)
__global__ void fill_pad_kernel(const int* __restrict__ cursor,
                                const int* __restrict__ row_ptr,
                                int* __restrict__ esrc, int Nn) {
  const int n = blockIdx.x * 256 + threadIdx.x;
  if (n >= Nn) return;
  const int end = row_ptr[n + 1];
  for (int p = cursor[n]; p < end; ++p) esrc[p] = Nn;
}

// --------------- FUSED softmax + aggregation (pull, no atomics) -----------
// H=4: one wave per node; lane owns 4 channels (short4); head = lane>>4.
// deg padded to x4 -> uniform 4-unrolled loop, no tail.
__global__ __launch_bounds__(256) void agg_fused_h4(
    const int* __restrict__ row_ptr, const int* __restrict__ esrc,
    const float* __restrict__ el, const float* __restrict__ er,
    const ushort* __restrict__ feat, const float* __restrict__ b,
    ushort* __restrict__ out, int Nn) {
  const int n = (blockIdx.x * 256 + threadIdx.x) >> 6;
  const int lane = threadIdx.x & 63;
  if (n >= Nn) return;
  const int h = lane >> 4;
  const int start = row_ptr[n];
  const int end = row_ptr[n + 1];
  const float erv = er[n * 4 + h];
  const short4* feat4 = (const short4*)feat;

  float den = 0.f;
  f32x4 acc = 0.f;
  for (int i = start; i < end; i += 4) {
    const int s0 = esrc[i], s1 = esrc[i + 1], s2 = esrc[i + 2],
              s3 = esrc[i + 3];
    const float x0 = el[s0 * 4 + h];
    const float x1 = el[s1 * 4 + h];
    const float x2 = el[s2 * 4 + h];
    const float x3 = el[s3 * 4 + h];
    const short4 f0 = feat4[(size_t)s0 * 64 + lane];
    const short4 f1 = feat4[(size_t)s1 * 64 + lane];
    const short4 f2 = feat4[(size_t)s2 * 64 + lane];
    const short4 f3 = feat4[(size_t)s3 * 64 + lane];
    const float e0 = lrelu_exp(x0 + erv), e1 = lrelu_exp(x1 + erv),
                e2 = lrelu_exp(x2 + erv), e3 = lrelu_exp(x3 + erv);
    den += (e0 + e1) + (e2 + e3);
    acc[0] += e0 * bf2f((ushort)f0.x) + e1 * bf2f((ushort)f1.x) +
              e2 * bf2f((ushort)f2.x) + e3 * bf2f((ushort)f3.x);
    acc[1] += e0 * bf2f((ushort)f0.y) + e1 * bf2f((ushort)f1.y) +
              e2 * bf2f((ushort)f2.y) + e3 * bf2f((ushort)f3.y);
    acc[2] += e0 * bf2f((ushort)f0.z) + e1 * bf2f((ushort)f1.z) +
              e2 * bf2f((ushort)f2.z) + e3 * bf2f((ushort)f3.z);
    acc[3] += e0 * bf2f((ushort)f0.w) + e1 * bf2f((ushort)f1.w) +
              e2 * bf2f((ushort)f2.w) + e3 * bf2f((ushort)f3.w);
  }
  const float rden = 1.f / den;
  const float4 bb = ((const float4*)b)[lane];
  short4 o;
  o.x = (short)f2bf(acc[0] * rden + bb.x);
  o.y = (short)f2bf(acc[1] * rden + bb.y);
  o.z = (short)f2bf(acc[2] * rden + bb.z);
  o.w = (short)f2bf(acc[3] * rden + bb.w);
  ((short4*)out)[(size_t)n * 64 + lane] = o;
}

// H=1: two nodes per wave; 32 lanes/node, lane owns 2 channels (uint load).
__global__ __launch_bounds__(256) void agg_fused_h1(
    const int* __restrict__ row_ptr, const int* __restrict__ esrc,
    const float* __restrict__ el, const float* __restrict__ er,
    const ushort* __restrict__ feat, const float* __restrict__ b,
    float* __restrict__ out, int Nn) {
  const int wid = (blockIdx.x * 256 + threadIdx.x) >> 6;
  const int lane = threadIdx.x & 63;
  const int n = wid * 2 + (lane >> 5);
  const int sub = lane & 31;
  if (n >= Nn) return;
  const int start = row_ptr[n];
  const int end = row_ptr[n + 1];
  const float erv = er[n];
  const uint* feat2 = (const uint*)feat;

  float den = 0.f;
  float a0 = 0.f, a1 = 0.f;
  for (int i = start; i < end; i += 4) {
    const int s0 = esrc[i], s1 = esrc[i + 1], s2 = esrc[i + 2],
              s3 = esrc[i + 3];
    const float x0 = el[s0], x1 = el[s1], x2 = el[s2], x3 = el[s3];
    const uint f0 = feat2[(size_t)s0 * 32 + sub];
    const uint f1 = feat2[(size_t)s1 * 32 + sub];
    const uint f2 = feat2[(size_t)s2 * 32 + sub];
    const uint f3 = feat2[(size_t)s3 * 32 + sub];
    const float e0 = lrelu_exp(x0 + erv), e1 = lrelu_exp(x1 + erv),
                e2 = lrelu_exp(x2 + erv), e3 = lrelu_exp(x3 + erv);
    den += (e0 + e1) + (e2 + e3);
    a0 += e0 * bf2f((ushort)(f0 & 0xffff)) + e1 * bf2f((ushort)(f1 & 0xffff)) +
          e2 * bf2f((ushort)(f2 & 0xffff)) + e3 * bf2f((ushort)(f3 & 0xffff));
    a1 += e0 * bf2f((ushort)(f0 >> 16)) + e1 * bf2f((ushort)(f1 >> 16)) +
          e2 * bf2f((ushort)(f2 >> 16)) + e3 * bf2f((ushort)(f3 >> 16));
  }
  const float rden = 1.f / den;
  const float2 bb = ((const float2*)b)[sub];
  float2 o;
  o.x = a0 * rden + bb.x;
  o.y = a1 * rden + bb.y;
  ((float2*)out)[(size_t)n * 32 + sub] = o;
}

// ------------------------------- driver -----------------------------------
static void run_layer(const ushort* hin, int K, int H, const float* W,
                      const float* al, const float* ar, const float* b,
                      ushort* Wt, ushort* feat, void* out, float* el,
                      float* er, const int* row_ptr, const int* esrc, int Nn,
                      hipStream_t stream) {
  const int HF = H * 64;
  convert_w_kernel<<<(K * HF + 255) / 256, 256, 0, stream>>>(W, Wt, K, HF);
  if (H == 4) {
    dim3 gg((Nn + 127) / 128, HF / 128);
    gemm_mfma<128><<<gg, 256, 0, stream>>>(hin, Wt, feat, Nn, K, HF);
    const int waves_grid = (Nn * 64 + 255) / 256;
    attn_coef_h4<<<waves_grid, 256, 0, stream>>>(feat, al, ar, el, er, Nn);
    agg_fused_h4<<<waves_grid, 256, 0, stream>>>(row_ptr, esrc, el, er, feat,
                                                 b, (ushort*)out, Nn);
  } else {
    dim3 gg((Nn + 127) / 128, HF / 64);
    gemm_mfma<64><<<gg, 256, 0, stream>>>(hin, Wt, feat, Nn, K, HF);
    attn_coef_h1<<<(Nn * 16 + 255) / 256, 256, 0, stream>>>(feat, al, ar, el,
                                                            er, Nn);
    agg_fused_h1<<<(Nn * 32 + 255) / 256, 256, 0, stream>>>(
        row_ptr, esrc, el, er, feat, b, (float*)out, Nn);
  }
}

extern "C" void kernel_launch(void* const* d_in, const int* in_sizes, int n_in,
                              void* d_out, int out_size, void* d_ws,
                              size_t ws_size, hipStream_t stream) {
  const float* nf = (const float*)d_in[0];
  const int* src = (const int*)d_in[1];
  const int* dst = (const int*)d_in[2];
  const float* W0 = (const float*)d_in[3];
  const float* al0 = (const float*)d_in[4];
  const float* ar0 = (const float*)d_in[5];
  const float* b0 = (const float*)d_in[6];
  const float* W1 = (const float*)d_in[7];
  const float* al1 = (const float*)d_in[8];
  const float* ar1 = (const float*)d_in[9];
  const float* b1 = (const float*)d_in[10];
  const float* W2 = (const float*)d_in[11];
  const float* al2 = (const float*)d_in[12];
  const float* ar2 = (const float*)d_in[13];
  const float* b2 = (const float*)d_in[14];

  const int IN = 128;
  const int Nn = in_sizes[0] / IN;
  const int E = in_sizes[1];
  const int ETP = E + 4 * Nn;  // padded-edge upper bound

  char* ws = (char*)d_ws;
  size_t off = 0;
  auto alloc = [&](size_t bytes) {
    char* p = ws + off;
    off += (bytes + 255) & ~(size_t)255;
    return p;
  };
  ushort* feat = (ushort*)alloc(((size_t)Nn + 1) * 256 * 2);  // +sentinel row
  ushort* h1 = (ushort*)alloc((size_t)Nn * 256 * 2);
  ushort* h2 = (ushort*)alloc((size_t)Nn * 256 * 2);
  ushort* a0 = (ushort*)alloc((size_t)Nn * 128 * 2);
  ushort* Wt = (ushort*)alloc((size_t)256 * 256 * 2);
  float* el = (float*)alloc(((size_t)Nn + 1) * 4 * 4);
  float* er = (float*)alloc((size_t)Nn * 4 * 4);
  int* row_ptr = (int*)alloc(((size_t)Nn + 1) * 4);
  int* cnt = (int*)alloc((size_t)Nn * 4);
  int* cursor = (int*)alloc((size_t)Nn * 4);
  int* esrc = (int*)alloc((size_t)ETP * 4);
  int* partials = (int*)alloc((size_t)1024 * 4);
  (void)ws_size;
  (void)n_in;
  (void)out_size;

  // zero feat sentinel row (gathered by padding edges with weight +0)
  hipMemsetAsync(feat + (size_t)Nn * 256, 0, 512, stream);

  // input fp32 -> bf16 once
  cvt_f32_bf16<<<(Nn * 16 + 255) / 256, 256, 0, stream>>>(nf, a0, Nn * 16);

  // ---- Build padded CSR over dst (reused by all 3 layers) ----
  const int ET = E + Nn;
  const int nb = (Nn + 1023) / 1024;
  hipMemsetAsync(cnt, 0, (size_t)Nn * sizeof(int), stream);
  hist_kernel<<<(ET + 255) / 256, 256, 0, stream>>>(dst, cnt, E, Nn);
  scan_blocks_kernel<<<nb, 1024, 0, stream>>>(cnt, row_ptr, partials, Nn);
  scan_partials_kernel<<<1, 1024, 0, stream>>>(partials, row_ptr, nb, Nn);
  add_offsets_kernel<<<nb, 1024, 0, stream>>>(row_ptr, cursor, partials, Nn);
  scatter_kernel<<<(ET + 255) / 256, 256, 0, stream>>>(src, dst, cursor, esrc,
                                                       E, Nn);
  fill_pad_kernel<<<(Nn + 255) / 256, 256, 0, stream>>>(cursor, row_ptr, esrc,
                                                        Nn);

  // Layer 0: [N,128] -> [N,256]
  run_layer(a0, IN, 4, W0, al0, ar0, b0, Wt, feat, h1, el, er, row_ptr, esrc,
            Nn, stream);
  // Layer 1: [N,256] -> [N,256]
  run_layer(h1, 256, 4, W1, al1, ar1, b1, Wt, feat, h2, el, er, row_ptr, esrc,
            Nn, stream);
  // Layer 2: [N,256] -> [N,64]
  run_layer(h2, 256, 1, W2, al2, ar2, b2, Wt, feat, d_out, el, er, row_ptr,
            esrc, Nn, stream);
}

// Round 7
// 224.821 us; speedup vs baseline: 5.8469x; 1.0492x over previous
//
#include <hip/hip_runtime.h>

// ---------------------------------------------------------------------------
// GAT 3-layer forward. bf16 MFMA GEMMs (BK=64, global_load_lds staging with
// both-sides XOR swizzle -> conflict-free ds_read_b128) + bf16 feat edge
// gather. CSR pull aggregation with fused edge-softmax, software-pipelined
// 4-edge groups (padded x4 with sentinel edges: src=Nn, el=-1e9 -> exp=+0).
// No float atomics. Softmax max-subtraction skipped (bounded exponents).
// ---------------------------------------------------------------------------

typedef __attribute__((ext_vector_type(8))) short short8;
typedef __attribute__((ext_vector_type(4))) float f32x4;

__device__ __forceinline__ float bf2f(ushort u) {
  union { unsigned int i; float f; } c;
  c.i = ((unsigned int)u) << 16;
  return c.f;
}
__device__ __forceinline__ ushort f2bf(float f) {
  union { float f; unsigned int i; } c;
  c.f = f;
  unsigned int u = c.i;
  u += 0x7FFFu + ((u >> 16) & 1u);
  return (ushort)(u >> 16);
}
__device__ __forceinline__ float lrelu_exp(float x) {
  const float y = fmaxf(x, 0.2f * x);
  return __expf(y);
}
__device__ __forceinline__ void gload_lds16(const ushort* g, void* lds) {
  __builtin_amdgcn_global_load_lds(
      (const __attribute__((address_space(1))) unsigned int*)g,
      (__attribute__((address_space(3))) unsigned int*)lds, 16, 0, 0);
}

// ------------------- prep: input cvt + all weight transposes ---------------
// job A: nf fp32 -> a0 bf16, n8 short8 units (blocks [0, nbA))
// job B: W0/W1/W2 fp32 [K][N] -> Wt bf16 [N][K]
__global__ __launch_bounds__(256) void prep_kernel(
    const float* __restrict__ nf, ushort* __restrict__ a0, int n8, int nbA,
    const float* __restrict__ W0, ushort* __restrict__ Wt0,
    const float* __restrict__ W1, ushort* __restrict__ Wt1,
    const float* __restrict__ W2, ushort* __restrict__ Wt2) {
  const int b = blockIdx.x;
  if (b < nbA) {
    const int i = b * 256 + threadIdx.x;
    if (i >= n8) return;
    const float4 v0 = ((const float4*)nf)[i * 2];
    const float4 v1 = ((const float4*)nf)[i * 2 + 1];
    short8 o;
    o[0] = (short)f2bf(v0.x); o[1] = (short)f2bf(v0.y);
    o[2] = (short)f2bf(v0.z); o[3] = (short)f2bf(v0.w);
    o[4] = (short)f2bf(v1.x); o[5] = (short)f2bf(v1.y);
    o[6] = (short)f2bf(v1.z); o[7] = (short)f2bf(v1.w);
    ((short8*)a0)[i] = o;
  } else {
    const int i = (b - nbA) * 256 + threadIdx.x;
    if (i < 32768) {  // W0: K=128, N=256
      const int k = i >> 8, n = i & 255;
      Wt0[n * 128 + k] = f2bf(W0[i]);
    } else if (i < 32768 + 65536) {  // W1: K=256, N=256
      const int j = i - 32768;
      const int k = j >> 8, n = j & 255;
      Wt1[n * 256 + k] = f2bf(W1[j]);
    } else if (i < 32768 + 65536 + 16384) {  // W2: K=256, N=64
      const int j = i - 32768 - 65536;
      const int k = j >> 6, n = j & 63;
      Wt2[n * 256 + k] = f2bf(W2[j]);
    }
  }
}

// ------------------------------ bf16 GEMM ----------------------------------
// A [M][K] bf16, Wt [Nc][K] bf16 -> C [M][Nc] bf16.
// BM=128, BN in {128,64}, BK=64; 256 thr = 4 waves (2 wm x 2 wn).
// LDS tile rows are 128B (64 bf16). Staging is LINEAR (global_load_lds);
// the k-slot is XOR-swizzled on the GLOBAL SOURCE side: LDS[row][slot]
// holds global k-slot (slot ^ (row&7)); reads apply the same XOR.
template <int BN>
__global__ __launch_bounds__(256) void gemm_mfma(
    const ushort* __restrict__ A, const ushort* __restrict__ Wt,
    ushort* __restrict__ C, int M, int K, int Nc) {
  constexpr int NF = BN / 32;          // n-frags per wave
  constexpr int NCHB = BN / 8;         // B chunks of 1KB
  __shared__ ushort As[128][64];
  __shared__ ushort Bs[BN][64];
  const int bm = blockIdx.x * 128;
  const int bn = blockIdx.y * BN;
  const int tid = threadIdx.x;
  const int lane = tid & 63;
  const int wave = tid >> 6;
  const int wm = wave >> 1;
  const int wn = wave & 1;
  const int lrow = lane >> 3;   // 0..7  (row within chunk)
  const int lslot = lane & 7;   // 16B slot within 128B row

  f32x4 acc[4][NF];
#pragma unroll
  for (int m = 0; m < 4; ++m)
#pragma unroll
    for (int n = 0; n < NF; ++n) acc[m][n] = 0.f;

  for (int k0 = 0; k0 < K; k0 += 64) {
    // ---- stage A: 16 chunks x 1KB; chunk c = rows [c*8, c*8+8) ----
#pragma unroll
    for (int c = wave; c < 16; c += 4) {
      const int row = c * 8 + lrow;
      int rg = bm + row;
      if (rg >= M) rg = M - 1;
      const int kcol = (lslot ^ (row & 7)) * 8;  // inverse-swizzled source
      gload_lds16(A + (size_t)rg * K + k0 + kcol,
                  (char*)(&As[0][0]) + c * 1024 + lrow * 128 + lslot * 16);
    }
    // ---- stage B ----
#pragma unroll
    for (int c = wave; c < NCHB; c += 4) {
      const int row = c * 8 + lrow;
      const int kcol = (lslot ^ (row & 7)) * 8;
      gload_lds16(Wt + (size_t)(bn + row) * K + k0 + kcol,
                  (char*)(&Bs[0][0]) + c * 1024 + lrow * 128 + lslot * 16);
    }
    __syncthreads();

#pragma unroll
    for (int kk = 0; kk < 2; ++kk) {
      short8 a[4], b[NF];
#pragma unroll
      for (int m = 0; m < 4; ++m) {
        const int row = wm * 64 + m * 16 + (lane & 15);
        const int slot = (kk * 4 + (lane >> 4)) ^ (row & 7);
        a[m] = *(const short8*)((const char*)&As[0][0] + row * 128 + slot * 16);
      }
#pragma unroll
      for (int n = 0; n < NF; ++n) {
        const int row = wn * (NF * 16) + n * 16 + (lane & 15);
        const int slot = (kk * 4 + (lane >> 4)) ^ (row & 7);
        b[n] = *(const short8*)((const char*)&Bs[0][0] + row * 128 + slot * 16);
      }
#pragma unroll
      for (int m = 0; m < 4; ++m)
#pragma unroll
        for (int n = 0; n < NF; ++n)
          acc[m][n] = __builtin_amdgcn_mfma_f32_16x16x32_bf16(
              a[m], b[n], acc[m][n], 0, 0, 0);
    }
    __syncthreads();
  }

#pragma unroll
  for (int m = 0; m < 4; ++m) {
#pragma unroll
    for (int r = 0; r < 4; ++r) {
      const int row = bm + wm * 64 + m * 16 + (lane >> 4) * 4 + r;
      if (row < M) {
#pragma unroll
        for (int n = 0; n < NF; ++n) {
          const int col = bn + wn * (NF * 16) + n * 16 + (lane & 15);
          C[(size_t)row * Nc + col] = f2bf(acc[m][n][r]);
        }
      }
    }
  }
}

// --------------------------- attn coefficients -----------------------------
__global__ __launch_bounds__(256) void attn_coef_h4(
    const ushort* __restrict__ feat, const float* __restrict__ al,
    const float* __restrict__ ar, float* __restrict__ el,
    float* __restrict__ er, int Nn) {
  if (blockIdx.x == 0 && threadIdx.x < 4) el[Nn * 4 + threadIdx.x] = -1e9f;
  const int n = (blockIdx.x * 256 + threadIdx.x) >> 6;
  const int lane = threadIdx.x & 63;
  if (n >= Nn) return;
  const short4 v = ((const short4*)(feat + (size_t)n * 256))[lane];
  const float4 a = ((const float4*)al)[lane];
  const float4 r = ((const float4*)ar)[lane];
  const float f0 = bf2f((ushort)v.x), f1 = bf2f((ushort)v.y),
              f2 = bf2f((ushort)v.z), f3 = bf2f((ushort)v.w);
  float pl = f0 * a.x + f1 * a.y + f2 * a.z + f3 * a.w;
  float pr = f0 * r.x + f1 * r.y + f2 * r.z + f3 * r.w;
#pragma unroll
  for (int off = 1; off < 16; off <<= 1) {
    pl += __shfl_xor(pl, off);
    pr += __shfl_xor(pr, off);
  }
  if ((lane & 15) == 0) {
    el[n * 4 + (lane >> 4)] = pl;
    er[n * 4 + (lane >> 4)] = pr;
  }
}

__global__ __launch_bounds__(256) void attn_coef_h1(
    const ushort* __restrict__ feat, const float* __restrict__ al,
    const float* __restrict__ ar, float* __restrict__ el,
    float* __restrict__ er, int Nn) {
  if (blockIdx.x == 0 && threadIdx.x == 0) el[Nn] = -1e9f;
  const int wid = (blockIdx.x * 256 + threadIdx.x) >> 6;
  const int lane = threadIdx.x & 63;
  const int n = wid * 4 + (lane >> 4);
  const int sub = lane & 15;
  if (n >= Nn) return;
  const short4 v = ((const short4*)(feat + (size_t)n * 64))[sub];
  const float4 a = ((const float4*)al)[sub];
  const float4 r = ((const float4*)ar)[sub];
  const float f0 = bf2f((ushort)v.x), f1 = bf2f((ushort)v.y),
              f2 = bf2f((ushort)v.z), f3 = bf2f((ushort)v.w);
  float pl = f0 * a.x + f1 * a.y + f2 * a.z + f3 * a.w;
  float pr = f0 * r.x + f1 * r.y + f2 * r.z + f3 * r.w;
#pragma unroll
  for (int off = 1; off < 16; off <<= 1) {
    pl += __shfl_xor(pl, off);
    pr += __shfl_xor(pr, off);
  }
  if (sub == 0) {
    el[n] = pl;
    er[n] = pr;
  }
}

// ------------------------- CSR construction (padded x4) --------------------
__global__ void hist_kernel(const int* __restrict__ dst, int* __restrict__ cnt,
                            int E, int Nn) {
  const int e = blockIdx.x * blockDim.x + threadIdx.x;
  if (e >= E + Nn) return;
  const int d = (e < E) ? dst[e] : (e - E);
  atomicAdd(&cnt[d], 1);
}

__device__ __forceinline__ int block_incl_scan_1024(int x, int* lds16) {
  const int lane = threadIdx.x & 63;
  const int wid = threadIdx.x >> 6;
  int inc = x;
#pragma unroll
  for (int off = 1; off < 64; off <<= 1) {
    const int y = __shfl_up(inc, off);
    if (lane >= off) inc += y;
  }
  if (lane == 63) lds16[wid] = inc;
  __syncthreads();
  if (wid == 0) {
    int t = (lane < 16) ? lds16[lane] : 0;
#pragma unroll
    for (int off = 1; off < 16; off <<= 1) {
      const int y = __shfl_up(t, off);
      if (lane >= off) t += y;
    }
    if (lane < 16) lds16[lane] = t;
  }
  __syncthreads();
  if (wid > 0) inc += lds16[wid - 1];
  return inc;
}

__global__ __launch_bounds__(1024) void scan_blocks_kernel(
    const int* __restrict__ cnt, int* __restrict__ row_ptr,
    int* __restrict__ partials, int n) {
  __shared__ int lds16[16];
  const int i = blockIdx.x * 1024 + threadIdx.x;
  const int x = (i < n) ? ((cnt[i] + 3) & ~3) : 0;
  const int inc = block_incl_scan_1024(x, lds16);
  if (i < n) row_ptr[i] = inc - x;
  if (threadIdx.x == 1023) partials[blockIdx.x] = inc;
}

__global__ __launch_bounds__(1024) void scan_partials_kernel(
    int* __restrict__ partials, int* __restrict__ row_ptr, int nb, int n) {
  __shared__ int lds16[16];
  const int x = (threadIdx.x < nb) ? partials[threadIdx.x] : 0;
  const int inc = block_incl_scan_1024(x, lds16);
  if (threadIdx.x < nb) partials[threadIdx.x] = inc - x;
  if (threadIdx.x == nb - 1) row_ptr[n] = inc;
}

__global__ __launch_bounds__(1024) void add_offsets_kernel(
    int* __restrict__ row_ptr, int* __restrict__ cursor,
    const int* __restrict__ partials, int n) {
  const int i = blockIdx.x * 1024 + threadIdx.x;
  if (i < n) {
    const int v = row_ptr[i] + partials[blockIdx.x];
    row_ptr[i] = v;
    cursor[i] = v;
  }
}

__global__ void scatter_kernel(const int* __restrict__ src,
                               const int* __restrict__ dst,
                               int* __restrict__ cursor, int* __restrict__ esrc,
                               int E, int Nn) {
  const int e = blockIdx.x * blockDim.x + threadIdx.x;
  if (e >= E + Nn) return;
  const int s = (e < E) ? src[e] : (e - E);
  const int d = (e < E) ? dst[e] : (e - E);
  const int pos = atomicAdd(&cursor[d], 1);
  esrc[pos] = s;
}

__global__ void fill_pad_kernel(const int* __restrict__ cursor,
                                const int* __restrict__ row_ptr,
                                int* __restrict__ esrc, int Nn) {
  const int n = blockIdx.x * 256 + threadIdx.x;
  if (n >= Nn) return;
  const int end = row_ptr[n + 1];
  for (int p = cursor[n]; p < end; ++p) esrc[p] = Nn;
}

// --------------- FUSED softmax + aggregation (pull, no atomics) -----------
// H=4: one wave per node; lane owns 4 channels (short4); head = lane>>4.
// Software-pipelined 4-edge groups: next group's loads issue before current
// group's math (2 groups in flight).
__global__ __launch_bounds__(256) void agg_fused_h4(
    const int* __restrict__ row_ptr, const int* __restrict__ esrc,
    const float* __restrict__ el, const float* __restrict__ er,
    const ushort* __restrict__ feat, const float* __restrict__ b,
    ushort* __restrict__ out, int Nn) {
  const int n = (blockIdx.x * 256 + threadIdx.x) >> 6;
  const int lane = threadIdx.x & 63;
  if (n >= Nn) return;
  const int h = lane >> 4;
  int i = row_ptr[n];
  const int end = row_ptr[n + 1];
  const float erv = er[n * 4 + h];
  const short4* fb = (const short4*)feat + lane;

  float den = 0.f;
  f32x4 acc = 0.f;
  // prologue: load group 0 (deg >= 1 padded to >= 4, always present)
  int s0 = esrc[i], s1 = esrc[i + 1], s2 = esrc[i + 2], s3 = esrc[i + 3];
  float x0 = el[s0 * 4 + h], x1 = el[s1 * 4 + h], x2 = el[s2 * 4 + h],
        x3 = el[s3 * 4 + h];
  short4 f0 = fb[(size_t)s0 * 64], f1 = fb[(size_t)s1 * 64],
         f2 = fb[(size_t)s2 * 64], f3 = fb[(size_t)s3 * 64];
  for (i += 4; i < end; i += 4) {
    // issue next group's loads
    const int t0 = esrc[i], t1 = esrc[i + 1], t2 = esrc[i + 2],
              t3 = esrc[i + 3];
    const float y0 = el[t0 * 4 + h], y1 = el[t1 * 4 + h], y2 = el[t2 * 4 + h],
                y3 = el[t3 * 4 + h];
    const short4 g0 = fb[(size_t)t0 * 64], g1 = fb[(size_t)t1 * 64],
                 g2 = fb[(size_t)t2 * 64], g3 = fb[(size_t)t3 * 64];
    // math on current group
    const float e0 = lrelu_exp(x0 + erv), e1 = lrelu_exp(x1 + erv),
                e2 = lrelu_exp(x2 + erv), e3 = lrelu_exp(x3 + erv);
    den += (e0 + e1) + (e2 + e3);
    acc[0] += e0 * bf2f((ushort)f0.x) + e1 * bf2f((ushort)f1.x) +
              e2 * bf2f((ushort)f2.x) + e3 * bf2f((ushort)f3.x);
    acc[1] += e0 * bf2f((ushort)f0.y) + e1 * bf2f((ushort)f1.y) +
              e2 * bf2f((ushort)f2.y) + e3 * bf2f((ushort)f3.y);
    acc[2] += e0 * bf2f((ushort)f0.z) + e1 * bf2f((ushort)f1.z) +
              e2 * bf2f((ushort)f2.z) + e3 * bf2f((ushort)f3.z);
    acc[3] += e0 * bf2f((ushort)f0.w) + e1 * bf2f((ushort)f1.w) +
              e2 * bf2f((ushort)f2.w) + e3 * bf2f((ushort)f3.w);
    x0 = y0; x1 = y1; x2 = y2; x3 = y3;
    f0 = g0; f1 = g1; f2 = g2; f3 = g3;
  }
  // epilogue: math on last group
  {
    const float e0 = lrelu_exp(x0 + erv), e1 = lrelu_exp(x1 + erv),
                e2 = lrelu_exp(x2 + erv), e3 = lrelu_exp(x3 + erv);
    den += (e0 + e1) + (e2 + e3);
    acc[0] += e0 * bf2f((ushort)f0.x) + e1 * bf2f((ushort)f1.x) +
              e2 * bf2f((ushort)f2.x) + e3 * bf2f((ushort)f3.x);
    acc[1] += e0 * bf2f((ushort)f0.y) + e1 * bf2f((ushort)f1.y) +
              e2 * bf2f((ushort)f2.y) + e3 * bf2f((ushort)f3.y);
    acc[2] += e0 * bf2f((ushort)f0.z) + e1 * bf2f((ushort)f1.z) +
              e2 * bf2f((ushort)f2.z) + e3 * bf2f((ushort)f3.z);
    acc[3] += e0 * bf2f((ushort)f0.w) + e1 * bf2f((ushort)f1.w) +
              e2 * bf2f((ushort)f2.w) + e3 * bf2f((ushort)f3.w);
  }
  const float rden = 1.f / den;
  const float4 bb = ((const float4*)b)[lane];
  short4 o;
  o.x = (short)f2bf(acc[0] * rden + bb.x);
  o.y = (short)f2bf(acc[1] * rden + bb.y);
  o.z = (short)f2bf(acc[2] * rden + bb.z);
  o.w = (short)f2bf(acc[3] * rden + bb.w);
  ((short4*)out)[(size_t)n * 64 + lane] = o;
}

// H=1: two nodes per wave; 32 lanes/node, lane owns 2 channels (uint load).
__global__ __launch_bounds__(256) void agg_fused_h1(
    const int* __restrict__ row_ptr, const int* __restrict__ esrc,
    const float* __restrict__ el, const float* __restrict__ er,
    const ushort* __restrict__ feat, const float* __restrict__ b,
    float* __restrict__ out, int Nn) {
  const int wid = (blockIdx.x * 256 + threadIdx.x) >> 6;
  const int lane = threadIdx.x & 63;
  const int n = wid * 2 + (lane >> 5);
  const int sub = lane & 31;
  if (n >= Nn) return;
  int i = row_ptr[n];
  const int end = row_ptr[n + 1];
  const float erv = er[n];
  const uint* fb = (const uint*)feat + sub;

  float den = 0.f;
  float a0 = 0.f, a1 = 0.f;
  int s0 = esrc[i], s1 = esrc[i + 1], s2 = esrc[i + 2], s3 = esrc[i + 3];
  float x0 = el[s0], x1 = el[s1], x2 = el[s2], x3 = el[s3];
  uint f0 = fb[(size_t)s0 * 32], f1 = fb[(size_t)s1 * 32],
       f2 = fb[(size_t)s2 * 32], f3 = fb[(size_t)s3 * 32];
  for (i += 4; i < end; i += 4) {
    const int t0 = esrc[i], t1 = esrc[i + 1], t2 = esrc[i + 2],
              t3 = esrc[i + 3];
    const float y0 = el[t0], y1 = el[t1], y2 = el[t2], y3 = el[t3];
    const uint g0 = fb[(size_t)t0 * 32], g1 = fb[(size_t)t1 * 32],
               g2 = fb[(size_t)t2 * 32], g3 = fb[(size_t)t3 * 32];
    const float e0 = lrelu_exp(x0 + erv), e1 = lrelu_exp(x1 + erv),
                e2 = lrelu_exp(x2 + erv), e3 = lrelu_exp(x3 + erv);
    den += (e0 + e1) + (e2 + e3);
    a0 += e0 * bf2f((ushort)(f0 & 0xffff)) + e1 * bf2f((ushort)(f1 & 0xffff)) +
          e2 * bf2f((ushort)(f2 & 0xffff)) + e3 * bf2f((ushort)(f3 & 0xffff));
    a1 += e0 * bf2f((ushort)(f0 >> 16)) + e1 * bf2f((ushort)(f1 >> 16)) +
          e2 * bf2f((ushort)(f2 >> 16)) + e3 * bf2f((ushort)(f3 >> 16));
    x0 = y0; x1 = y1; x2 = y2; x3 = y3;
    f0 = g0; f1 = g1; f2 = g2; f3 = g3;
  }
  {
    const float e0 = lrelu_exp(x0 + erv), e1 = lrelu_exp(x1 + erv),
                e2 = lrelu_exp(x2 + erv), e3 = lrelu_exp(x3 + erv);
    den += (e0 + e1) + (e2 + e3);
    a0 += e0 * bf2f((ushort)(f0 & 0xffff)) + e1 * bf2f((ushort)(f1 & 0xffff)) +
          e2 * bf2f((ushort)(f2 & 0xffff)) + e3 * bf2f((ushort)(f3 & 0xffff));
    a1 += e0 * bf2f((ushort)(f0 >> 16)) + e1 * bf2f((ushort)(f1 >> 16)) +
          e2 * bf2f((ushort)(f2 >> 16)) + e3 * bf2f((ushort)(f3 >> 16));
  }
  const float rden = 1.f / den;
  const float2 bb = ((const float2*)b)[sub];
  float2 o;
  o.x = a0 * rden + bb.x;
  o.y = a1 * rden + bb.y;
  ((float2*)out)[(size_t)n * 32 + sub] = o;
}

// ------------------------------- driver -----------------------------------
static void run_layer(const ushort* hin, int K, int H, const ushort* Wt,
                      const float* al, const float* ar, const float* b,
                      ushort* feat, void* out, float* el, float* er,
                      const int* row_ptr, const int* esrc, int Nn,
                      hipStream_t stream) {
  const int HF = H * 64;
  if (H == 4) {
    dim3 gg((Nn + 127) / 128, HF / 128);
    gemm_mfma<128><<<gg, 256, 0, stream>>>(hin, Wt, feat, Nn, K, HF);
    const int waves_grid = (Nn * 64 + 255) / 256;
    attn_coef_h4<<<waves_grid, 256, 0, stream>>>(feat, al, ar, el, er, Nn);
    agg_fused_h4<<<waves_grid, 256, 0, stream>>>(row_ptr, esrc, el, er, feat,
                                                 b, (ushort*)out, Nn);
  } else {
    dim3 gg((Nn + 127) / 128, HF / 64);
    gemm_mfma<64><<<gg, 256, 0, stream>>>(hin, Wt, feat, Nn, K, HF);
    attn_coef_h1<<<(Nn * 16 + 255) / 256, 256, 0, stream>>>(feat, al, ar, el,
                                                            er, Nn);
    agg_fused_h1<<<(Nn * 32 + 255) / 256, 256, 0, stream>>>(
        row_ptr, esrc, el, er, feat, b, (float*)out, Nn);
  }
}

extern "C" void kernel_launch(void* const* d_in, const int* in_sizes, int n_in,
                              void* d_out, int out_size, void* d_ws,
                              size_t ws_size, hipStream_t stream) {
  const float* nf = (const float*)d_in[0];
  const int* src = (const int*)d_in[1];
  const int* dst = (const int*)d_in[2];
  const float* W0 = (const float*)d_in[3];
  const float* al0 = (const float*)d_in[4];
  const float* ar0 = (const float*)d_in[5];
  const float* b0 = (const float*)d_in[6];
  const float* W1 = (const float*)d_in[7];
  const float* al1 = (const float*)d_in[8];
  const float* ar1 = (const float*)d_in[9];
  const float* b1 = (const float*)d_in[10];
  const float* W2 = (const float*)d_in[11];
  const float* al2 = (const float*)d_in[12];
  const float* ar2 = (const float*)d_in[13];
  const float* b2 = (const float*)d_in[14];

  const int IN = 128;
  const int Nn = in_sizes[0] / IN;
  const int E = in_sizes[1];
  const int ETP = E + 4 * Nn;  // padded-edge upper bound

  char* ws = (char*)d_ws;
  size_t off = 0;
  auto alloc = [&](size_t bytes) {
    char* p = ws + off;
    off += (bytes + 255) & ~(size_t)255;
    return p;
  };
  ushort* feat = (ushort*)alloc(((size_t)Nn + 1) * 256 * 2);  // +sentinel row
  ushort* h1 = (ushort*)alloc((size_t)Nn * 256 * 2);
  ushort* h2 = (ushort*)alloc((size_t)Nn * 256 * 2);
  ushort* a0 = (ushort*)alloc((size_t)Nn * 128 * 2);
  ushort* Wt0 = (ushort*)alloc((size_t)256 * 128 * 2);
  ushort* Wt1 = (ushort*)alloc((size_t)256 * 256 * 2);
  ushort* Wt2 = (ushort*)alloc((size_t)64 * 256 * 2);
  float* el = (float*)alloc(((size_t)Nn + 1) * 4 * 4);
  float* er = (float*)alloc((size_t)Nn * 4 * 4);
  int* row_ptr = (int*)alloc(((size_t)Nn + 1) * 4);
  int* cnt = (int*)alloc((size_t)Nn * 4);
  int* cursor = (int*)alloc((size_t)Nn * 4);
  int* esrc = (int*)alloc((size_t)ETP * 4);
  int* partials = (int*)alloc((size_t)1024 * 4);
  (void)ws_size;
  (void)n_in;
  (void)out_size;

  // zero feat sentinel row (gathered by padding edges with weight +0)
  hipMemsetAsync(feat + (size_t)Nn * 256, 0, 512, stream);

  // prep: input cvt + all 3 weight transposes in one launch
  const int n8 = Nn * 16;
  const int nbA = (n8 + 255) / 256;
  const int nbB = (32768 + 65536 + 16384 + 255) / 256;
  prep_kernel<<<nbA + nbB, 256, 0, stream>>>(nf, a0, n8, nbA, W0, Wt0, W1, Wt1,
                                             W2, Wt2);

  // ---- Build padded CSR over dst (reused by all 3 layers) ----
  const int ET = E + Nn;
  const int nb = (Nn + 1023) / 1024;
  hipMemsetAsync(cnt, 0, (size_t)Nn * sizeof(int), stream);
  hist_kernel<<<(ET + 255) / 256, 256, 0, stream>>>(dst, cnt, E, Nn);
  scan_blocks_kernel<<<nb, 1024, 0, stream>>>(cnt, row_ptr, partials, Nn);
  scan_partials_kernel<<<1, 1024, 0, stream>>>(partials, row_ptr, nb, Nn);
  add_offsets_kernel<<<nb, 1024, 0, stream>>>(row_ptr, cursor, partials, Nn);
  scatter_kernel<<<(ET + 255) / 256, 256, 0, stream>>>(src, dst, cursor, esrc,
                                                       E, Nn);
  fill_pad_kernel<<<(Nn + 255) / 256, 256, 0, stream>>>(cursor, row_ptr, esrc,
                                                        Nn);

  // Layer 0: [N,128] -> [N,256]
  run_layer(a0, IN, 4, Wt0, al0, ar0, b0, feat, h1, el, er, row_ptr, esrc, Nn,
            stream);
  // Layer 1: [N,256] -> [N,256]
  run_layer(h1, 256, 4, Wt1, al1, ar1, b1, feat, h2, el, er, row_ptr, esrc, Nn,
            stream);
  // Layer 2: [N,256] -> [N,64]
  run_layer(h2, 256, 1, Wt2, al2, ar2, b2, feat, d_out, el, er, row_ptr, esrc,
            Nn, stream);
}

// Round 8
// 211.796 us; speedup vs baseline: 6.2065x; 1.0615x over previous
//
#include <hip/hip_runtime.h>

// ---------------------------------------------------------------------------
// GAT 3-layer forward. bf16 MFMA GEMMs (BK=64, global_load_lds staging, XOR
// swizzle) with attn-coefficient computation FUSED into the H=4 GEMM epilogue
// (each wave's 64-col span == one head -> in-wave shuffle reduce). CSR pull
// aggregation with fused edge-softmax, software-pipelined 4-edge groups
// (padded x4 with sentinel edges: src=Nn, el=-1e9 -> exp=+0). No float
// atomics, NO hipMemsetAsync in the timed path (runtime fill kernel for small
// sizes costs ~41 us); all zeroing/sentinels done inside prep_kernel.
// Softmax max-subtraction skipped (bounded exponents, fp32 exp safe).
// ---------------------------------------------------------------------------

typedef __attribute__((ext_vector_type(8))) short short8;
typedef __attribute__((ext_vector_type(4))) float f32x4;
typedef __attribute__((ext_vector_type(4))) int int4v;

__device__ __forceinline__ float bf2f(ushort u) {
  union { unsigned int i; float f; } c;
  c.i = ((unsigned int)u) << 16;
  return c.f;
}
__device__ __forceinline__ ushort f2bf(float f) {
  union { float f; unsigned int i; } c;
  c.f = f;
  unsigned int u = c.i;
  u += 0x7FFFu + ((u >> 16) & 1u);
  return (ushort)(u >> 16);
}
__device__ __forceinline__ float lrelu_exp(float x) {
  const float y = fmaxf(x, 0.2f * x);
  return __expf(y);
}
__device__ __forceinline__ void gload_lds16(const ushort* g, void* lds) {
  __builtin_amdgcn_global_load_lds(
      (const __attribute__((address_space(1))) unsigned int*)g,
      (__attribute__((address_space(3))) unsigned int*)lds, 16, 0, 0);
}

// ------------- prep: cvt + weight transposes + zeroing + sentinels ---------
// blocks [0,nbA): nf fp32 -> a0 bf16
// blocks [nbA, nbA+nbW): W0/W1/W2 fp32 [K][N] -> Wt bf16 [N][K]
// blocks [nbA+nbW, nbA+nbW+nbZ): zero cnt[Nn]
// last block: feat sentinel row zero + el sentinels
__global__ __launch_bounds__(256) void prep_kernel(
    const float* __restrict__ nf, ushort* __restrict__ a0, int n8, int nbA,
    const float* __restrict__ W0, ushort* __restrict__ Wt0,
    const float* __restrict__ W1, ushort* __restrict__ Wt1,
    const float* __restrict__ W2, ushort* __restrict__ Wt2, int nbW,
    int* __restrict__ cnt, int Nn, int nbZ, ushort* __restrict__ feat_sent,
    float* __restrict__ el4, float* __restrict__ el1) {
  const int b = blockIdx.x;
  if (b < nbA) {
    const int i = b * 256 + threadIdx.x;
    if (i >= n8) return;
    const float4 v0 = ((const float4*)nf)[i * 2];
    const float4 v1 = ((const float4*)nf)[i * 2 + 1];
    short8 o;
    o[0] = (short)f2bf(v0.x); o[1] = (short)f2bf(v0.y);
    o[2] = (short)f2bf(v0.z); o[3] = (short)f2bf(v0.w);
    o[4] = (short)f2bf(v1.x); o[5] = (short)f2bf(v1.y);
    o[6] = (short)f2bf(v1.z); o[7] = (short)f2bf(v1.w);
    ((short8*)a0)[i] = o;
  } else if (b < nbA + nbW) {
    const int i = (b - nbA) * 256 + threadIdx.x;
    if (i < 32768) {  // W0: K=128, N=256
      const int k = i >> 8, n = i & 255;
      Wt0[n * 128 + k] = f2bf(W0[i]);
    } else if (i < 32768 + 65536) {  // W1: K=256, N=256
      const int j = i - 32768;
      const int k = j >> 8, n = j & 255;
      Wt1[n * 256 + k] = f2bf(W1[j]);
    } else if (i < 32768 + 65536 + 16384) {  // W2: K=256, N=64
      const int j = i - 32768 - 65536;
      const int k = j >> 6, n = j & 63;
      Wt2[n * 256 + k] = f2bf(W2[j]);
    }
  } else if (b < nbA + nbW + nbZ) {
    const int idx = (b - nbA - nbW) * 256 + threadIdx.x;  // int4 units
    const int base = idx * 4;
    if (base + 4 <= Nn) {
      ((int4v*)cnt)[idx] = (int4v)0;
    } else if (base < Nn) {
      for (int j = base; j < Nn; ++j) cnt[j] = 0;
    }
  } else {
    const int t = threadIdx.x;
    if (t < 128) ((uint*)feat_sent)[t] = 0u;  // 256 ushorts
    if (t >= 128 && t < 132) el4[(size_t)Nn * 4 + (t - 128)] = -1e9f;
    if (t == 132) el1[Nn] = -1e9f;
  }
}

// ------------------------------ bf16 GEMM ----------------------------------
// A [M][K] bf16, Wt [Nc][K] bf16 -> C [M][Nc] bf16.
// BM=128, BN in {128,64}, BK=64; 256 thr = 4 waves (2 wm x 2 wn).
// LDS rows 128B; k-slot XOR-swizzled on the GLOBAL SOURCE side (linear LDS
// dest for global_load_lds), reads apply the same XOR.
// FUSE (BN=128 only): el/er[row][head] computed from fp32 acc in epilogue;
// head = blockIdx.y*2 + wn (wave col span == one head).
template <int BN, bool FUSE>
__global__ __launch_bounds__(256) void gemm_mfma(
    const ushort* __restrict__ A, const ushort* __restrict__ Wt,
    ushort* __restrict__ C, int M, int K, int Nc,
    const float* __restrict__ al, const float* __restrict__ ar,
    float* __restrict__ el, float* __restrict__ er) {
  constexpr int NF = BN / 32;
  constexpr int NCHB = BN / 8;
  __shared__ ushort As[128][64];
  __shared__ ushort Bs[BN][64];
  const int bm = blockIdx.x * 128;
  const int bn = blockIdx.y * BN;
  const int tid = threadIdx.x;
  const int lane = tid & 63;
  const int wave = tid >> 6;
  const int wm = wave >> 1;
  const int wn = wave & 1;
  const int lrow = lane >> 3;
  const int lslot = lane & 7;

  f32x4 acc[4][NF];
#pragma unroll
  for (int m = 0; m < 4; ++m)
#pragma unroll
    for (int n = 0; n < NF; ++n) acc[m][n] = 0.f;

  for (int k0 = 0; k0 < K; k0 += 64) {
#pragma unroll
    for (int c = wave; c < 16; c += 4) {
      const int row = c * 8 + lrow;
      int rg = bm + row;
      if (rg >= M) rg = M - 1;
      const int kcol = (lslot ^ (row & 7)) * 8;
      gload_lds16(A + (size_t)rg * K + k0 + kcol,
                  (char*)(&As[0][0]) + c * 1024 + lrow * 128 + lslot * 16);
    }
#pragma unroll
    for (int c = wave; c < NCHB; c += 4) {
      const int row = c * 8 + lrow;
      const int kcol = (lslot ^ (row & 7)) * 8;
      gload_lds16(Wt + (size_t)(bn + row) * K + k0 + kcol,
                  (char*)(&Bs[0][0]) + c * 1024 + lrow * 128 + lslot * 16);
    }
    __syncthreads();

#pragma unroll
    for (int kk = 0; kk < 2; ++kk) {
      short8 a[4], b[NF];
#pragma unroll
      for (int m = 0; m < 4; ++m) {
        const int row = wm * 64 + m * 16 + (lane & 15);
        const int slot = (kk * 4 + (lane >> 4)) ^ (row & 7);
        a[m] = *(const short8*)((const char*)&As[0][0] + row * 128 + slot * 16);
      }
#pragma unroll
      for (int n = 0; n < NF; ++n) {
        const int row = wn * (NF * 16) + n * 16 + (lane & 15);
        const int slot = (kk * 4 + (lane >> 4)) ^ (row & 7);
        b[n] = *(const short8*)((const char*)&Bs[0][0] + row * 128 + slot * 16);
      }
#pragma unroll
      for (int m = 0; m < 4; ++m)
#pragma unroll
        for (int n = 0; n < NF; ++n)
          acc[m][n] = __builtin_amdgcn_mfma_f32_16x16x32_bf16(
              a[m], b[n], acc[m][n], 0, 0, 0);
    }
    __syncthreads();
  }

#pragma unroll
  for (int m = 0; m < 4; ++m) {
#pragma unroll
    for (int r = 0; r < 4; ++r) {
      const int row = bm + wm * 64 + m * 16 + (lane >> 4) * 4 + r;
      if (row < M) {
#pragma unroll
        for (int n = 0; n < NF; ++n) {
          const int col = bn + wn * (NF * 16) + n * 16 + (lane & 15);
          C[(size_t)row * Nc + col] = f2bf(acc[m][n][r]);
        }
      }
    }
  }

  if constexpr (FUSE) {
    const int cc = lane & 15;
    const int head = blockIdx.y * 2 + wn;
    float alv[NF], arv[NF];
#pragma unroll
    for (int n = 0; n < NF; ++n) {
      alv[n] = al[head * 64 + n * 16 + cc];
      arv[n] = ar[head * 64 + n * 16 + cc];
    }
#pragma unroll
    for (int m = 0; m < 4; ++m) {
#pragma unroll
      for (int r = 0; r < 4; ++r) {
        float pl = 0.f, pr = 0.f;
#pragma unroll
        for (int n = 0; n < NF; ++n) {
          pl = fmaf(acc[m][n][r], alv[n], pl);
          pr = fmaf(acc[m][n][r], arv[n], pr);
        }
#pragma unroll
        for (int o = 1; o < 16; o <<= 1) {
          pl += __shfl_xor(pl, o);
          pr += __shfl_xor(pr, o);
        }
        if (cc == 0) {
          const int row = bm + wm * 64 + m * 16 + (lane >> 4) * 4 + r;
          if (row < M) {
            el[row * 4 + head] = pl;
            er[row * 4 + head] = pr;
          }
        }
      }
    }
  }
}

// --------------------------- attn coefficients (H=1) -----------------------
__global__ __launch_bounds__(256) void attn_coef_h1(
    const ushort* __restrict__ feat, const float* __restrict__ al,
    const float* __restrict__ ar, float* __restrict__ el,
    float* __restrict__ er, int Nn) {
  const int wid = (blockIdx.x * 256 + threadIdx.x) >> 6;
  const int lane = threadIdx.x & 63;
  const int n = wid * 4 + (lane >> 4);
  const int sub = lane & 15;
  if (n >= Nn) return;
  const short4 v = ((const short4*)(feat + (size_t)n * 64))[sub];
  const float4 a = ((const float4*)al)[sub];
  const float4 r = ((const float4*)ar)[sub];
  const float f0 = bf2f((ushort)v.x), f1 = bf2f((ushort)v.y),
              f2 = bf2f((ushort)v.z), f3 = bf2f((ushort)v.w);
  float pl = f0 * a.x + f1 * a.y + f2 * a.z + f3 * a.w;
  float pr = f0 * r.x + f1 * r.y + f2 * r.z + f3 * r.w;
#pragma unroll
  for (int off = 1; off < 16; off <<= 1) {
    pl += __shfl_xor(pl, off);
    pr += __shfl_xor(pr, off);
  }
  if (sub == 0) {
    el[n] = pl;
    er[n] = pr;
  }
}

// ------------------------- CSR construction (padded x4) --------------------
__global__ void hist_kernel(const int* __restrict__ dst, int* __restrict__ cnt,
                            int E, int Nn) {
  const int e = blockIdx.x * blockDim.x + threadIdx.x;
  if (e >= E + Nn) return;
  const int d = (e < E) ? dst[e] : (e - E);
  atomicAdd(&cnt[d], 1);
}

__device__ __forceinline__ int block_incl_scan_1024(int x, int* lds16) {
  const int lane = threadIdx.x & 63;
  const int wid = threadIdx.x >> 6;
  int inc = x;
#pragma unroll
  for (int off = 1; off < 64; off <<= 1) {
    const int y = __shfl_up(inc, off);
    if (lane >= off) inc += y;
  }
  if (lane == 63) lds16[wid] = inc;
  __syncthreads();
  if (wid == 0) {
    int t = (lane < 16) ? lds16[lane] : 0;
#pragma unroll
    for (int off = 1; off < 16; off <<= 1) {
      const int y = __shfl_up(t, off);
      if (lane >= off) t += y;
    }
    if (lane < 16) lds16[lane] = t;
  }
  __syncthreads();
  if (wid > 0) inc += lds16[wid - 1];
  return inc;
}

__global__ __launch_bounds__(1024) void scan_blocks_kernel(
    const int* __restrict__ cnt, int* __restrict__ row_ptr,
    int* __restrict__ partials, int n) {
  __shared__ int lds16[16];
  const int i = blockIdx.x * 1024 + threadIdx.x;
  const int x = (i < n) ? ((cnt[i] + 3) & ~3) : 0;
  const int inc = block_incl_scan_1024(x, lds16);
  if (i < n) row_ptr[i] = inc - x;
  if (threadIdx.x == 1023) partials[blockIdx.x] = inc;
}

__global__ __launch_bounds__(1024) void scan_partials_kernel(
    int* __restrict__ partials, int* __restrict__ row_ptr, int nb, int n) {
  __shared__ int lds16[16];
  const int x = (threadIdx.x < nb) ? partials[threadIdx.x] : 0;
  const int inc = block_incl_scan_1024(x, lds16);
  if (threadIdx.x < nb) partials[threadIdx.x] = inc - x;
  if (threadIdx.x == nb - 1) row_ptr[n] = inc;
}

__global__ __launch_bounds__(1024) void add_offsets_kernel(
    int* __restrict__ row_ptr, int* __restrict__ cursor,
    const int* __restrict__ partials, int n) {
  const int i = blockIdx.x * 1024 + threadIdx.x;
  if (i < n) {
    const int v = row_ptr[i] + partials[blockIdx.x];
    row_ptr[i] = v;
    cursor[i] = v;
  }
}

__global__ void scatter_kernel(const int* __restrict__ src,
                               const int* __restrict__ dst,
                               int* __restrict__ cursor, int* __restrict__ esrc,
                               int E, int Nn) {
  const int e = blockIdx.x * blockDim.x + threadIdx.x;
  if (e >= E + Nn) return;
  const int s = (e < E) ? src[e] : (e - E);
  const int d = (e < E) ? dst[e] : (e - E);
  const int pos = atomicAdd(&cursor[d], 1);
  esrc[pos] = s;
}

__global__ void fill_pad_kernel(const int* __restrict__ cursor,
                                const int* __restrict__ row_ptr,
                                int* __restrict__ esrc, int Nn) {
  const int n = blockIdx.x * 256 + threadIdx.x;
  if (n >= Nn) return;
  const int end = row_ptr[n + 1];
  for (int p = cursor[n]; p < end; ++p) esrc[p] = Nn;
}

// --------------- FUSED softmax + aggregation (pull, no atomics) -----------
__global__ __launch_bounds__(256) void agg_fused_h4(
    const int* __restrict__ row_ptr, const int* __restrict__ esrc,
    const float* __restrict__ el, const float* __restrict__ er,
    const ushort* __restrict__ feat, const float* __restrict__ b,
    ushort* __restrict__ out, int Nn) {
  const int n = (blockIdx.x * 256 + threadIdx.x) >> 6;
  const int lane = threadIdx.x & 63;
  if (n >= Nn) return;
  const int h = lane >> 4;
  int i = row_ptr[n];
  const int end = row_ptr[n + 1];
  const float erv = er[n * 4 + h];
  const short4* fb = (const short4*)feat + lane;

  float den = 0.f;
  f32x4 acc = 0.f;
  int s0 = esrc[i], s1 = esrc[i + 1], s2 = esrc[i + 2], s3 = esrc[i + 3];
  float x0 = el[s0 * 4 + h], x1 = el[s1 * 4 + h], x2 = el[s2 * 4 + h],
        x3 = el[s3 * 4 + h];
  short4 f0 = fb[(size_t)s0 * 64], f1 = fb[(size_t)s1 * 64],
         f2 = fb[(size_t)s2 * 64], f3 = fb[(size_t)s3 * 64];
  for (i += 4; i < end; i += 4) {
    const int t0 = esrc[i], t1 = esrc[i + 1], t2 = esrc[i + 2],
              t3 = esrc[i + 3];
    const float y0 = el[t0 * 4 + h], y1 = el[t1 * 4 + h], y2 = el[t2 * 4 + h],
                y3 = el[t3 * 4 + h];
    const short4 g0 = fb[(size_t)t0 * 64], g1 = fb[(size_t)t1 * 64],
                 g2 = fb[(size_t)t2 * 64], g3 = fb[(size_t)t3 * 64];
    const float e0 = lrelu_exp(x0 + erv), e1 = lrelu_exp(x1 + erv),
                e2 = lrelu_exp(x2 + erv), e3 = lrelu_exp(x3 + erv);
    den += (e0 + e1) + (e2 + e3);
    acc[0] += e0 * bf2f((ushort)f0.x) + e1 * bf2f((ushort)f1.x) +
              e2 * bf2f((ushort)f2.x) + e3 * bf2f((ushort)f3.x);
    acc[1] += e0 * bf2f((ushort)f0.y) + e1 * bf2f((ushort)f1.y) +
              e2 * bf2f((ushort)f2.y) + e3 * bf2f((ushort)f3.y);
    acc[2] += e0 * bf2f((ushort)f0.z) + e1 * bf2f((ushort)f1.z) +
              e2 * bf2f((ushort)f2.z) + e3 * bf2f((ushort)f3.z);
    acc[3] += e0 * bf2f((ushort)f0.w) + e1 * bf2f((ushort)f1.w) +
              e2 * bf2f((ushort)f2.w) + e3 * bf2f((ushort)f3.w);
    x0 = y0; x1 = y1; x2 = y2; x3 = y3;
    f0 = g0; f1 = g1; f2 = g2; f3 = g3;
  }
  {
    const float e0 = lrelu_exp(x0 + erv), e1 = lrelu_exp(x1 + erv),
                e2 = lrelu_exp(x2 + erv), e3 = lrelu_exp(x3 + erv);
    den += (e0 + e1) + (e2 + e3);
    acc[0] += e0 * bf2f((ushort)f0.x) + e1 * bf2f((ushort)f1.x) +
              e2 * bf2f((ushort)f2.x) + e3 * bf2f((ushort)f3.x);
    acc[1] += e0 * bf2f((ushort)f0.y) + e1 * bf2f((ushort)f1.y) +
              e2 * bf2f((ushort)f2.y) + e3 * bf2f((ushort)f3.y);
    acc[2] += e0 * bf2f((ushort)f0.z) + e1 * bf2f((ushort)f1.z) +
              e2 * bf2f((ushort)f2.z) + e3 * bf2f((ushort)f3.z);
    acc[3] += e0 * bf2f((ushort)f0.w) + e1 * bf2f((ushort)f1.w) +
              e2 * bf2f((ushort)f2.w) + e3 * bf2f((ushort)f3.w);
  }
  const float rden = 1.f / den;
  const float4 bb = ((const float4*)b)[lane];
  short4 o;
  o.x = (short)f2bf(acc[0] * rden + bb.x);
  o.y = (short)f2bf(acc[1] * rden + bb.y);
  o.z = (short)f2bf(acc[2] * rden + bb.z);
  o.w = (short)f2bf(acc[3] * rden + bb.w);
  ((short4*)out)[(size_t)n * 64 + lane] = o;
}

__global__ __launch_bounds__(256) void agg_fused_h1(
    const int* __restrict__ row_ptr, const int* __restrict__ esrc,
    const float* __restrict__ el, const float* __restrict__ er,
    const ushort* __restrict__ feat, const float* __restrict__ b,
    float* __restrict__ out, int Nn) {
  const int wid = (blockIdx.x * 256 + threadIdx.x) >> 6;
  const int lane = threadIdx.x & 63;
  const int n = wid * 2 + (lane >> 5);
  const int sub = lane & 31;
  if (n >= Nn) return;
  int i = row_ptr[n];
  const int end = row_ptr[n + 1];
  const float erv = er[n];
  const uint* fb = (const uint*)feat + sub;

  float den = 0.f;
  float a0 = 0.f, a1 = 0.f;
  int s0 = esrc[i], s1 = esrc[i + 1], s2 = esrc[i + 2], s3 = esrc[i + 3];
  float x0 = el[s0], x1 = el[s1], x2 = el[s2], x3 = el[s3];
  uint f0 = fb[(size_t)s0 * 32], f1 = fb[(size_t)s1 * 32],
       f2 = fb[(size_t)s2 * 32], f3 = fb[(size_t)s3 * 32];
  for (i += 4; i < end; i += 4) {
    const int t0 = esrc[i], t1 = esrc[i + 1], t2 = esrc[i + 2],
              t3 = esrc[i + 3];
    const float y0 = el[t0], y1 = el[t1], y2 = el[t2], y3 = el[t3];
    const uint g0 = fb[(size_t)t0 * 32], g1 = fb[(size_t)t1 * 32],
               g2 = fb[(size_t)t2 * 32], g3 = fb[(size_t)t3 * 32];
    const float e0 = lrelu_exp(x0 + erv), e1 = lrelu_exp(x1 + erv),
                e2 = lrelu_exp(x2 + erv), e3 = lrelu_exp(x3 + erv);
    den += (e0 + e1) + (e2 + e3);
    a0 += e0 * bf2f((ushort)(f0 & 0xffff)) + e1 * bf2f((ushort)(f1 & 0xffff)) +
          e2 * bf2f((ushort)(f2 & 0xffff)) + e3 * bf2f((ushort)(f3 & 0xffff));
    a1 += e0 * bf2f((ushort)(f0 >> 16)) + e1 * bf2f((ushort)(f1 >> 16)) +
          e2 * bf2f((ushort)(f2 >> 16)) + e3 * bf2f((ushort)(f3 >> 16));
    x0 = y0; x1 = y1; x2 = y2; x3 = y3;
    f0 = g0; f1 = g1; f2 = g2; f3 = g3;
  }
  {
    const float e0 = lrelu_exp(x0 + erv), e1 = lrelu_exp(x1 + erv),
                e2 = lrelu_exp(x2 + erv), e3 = lrelu_exp(x3 + erv);
    den += (e0 + e1) + (e2 + e3);
    a0 += e0 * bf2f((ushort)(f0 & 0xffff)) + e1 * bf2f((ushort)(f1 & 0xffff)) +
          e2 * bf2f((ushort)(f2 & 0xffff)) + e3 * bf2f((ushort)(f3 & 0xffff));
    a1 += e0 * bf2f((ushort)(f0 >> 16)) + e1 * bf2f((ushort)(f1 >> 16)) +
          e2 * bf2f((ushort)(f2 >> 16)) + e3 * bf2f((ushort)(f3 >> 16));
  }
  const float rden = 1.f / den;
  const float2 bb = ((const float2*)b)[sub];
  float2 o;
  o.x = a0 * rden + bb.x;
  o.y = a1 * rden + bb.y;
  ((float2*)out)[(size_t)n * 32 + sub] = o;
}

// ------------------------------- driver -----------------------------------
extern "C" void kernel_launch(void* const* d_in, const int* in_sizes, int n_in,
                              void* d_out, int out_size, void* d_ws,
                              size_t ws_size, hipStream_t stream) {
  const float* nf = (const float*)d_in[0];
  const int* src = (const int*)d_in[1];
  const int* dst = (const int*)d_in[2];
  const float* W0 = (const float*)d_in[3];
  const float* al0 = (const float*)d_in[4];
  const float* ar0 = (const float*)d_in[5];
  const float* b0 = (const float*)d_in[6];
  const float* W1 = (const float*)d_in[7];
  const float* al1 = (const float*)d_in[8];
  const float* ar1 = (const float*)d_in[9];
  const float* b1 = (const float*)d_in[10];
  const float* W2 = (const float*)d_in[11];
  const float* al2 = (const float*)d_in[12];
  const float* ar2 = (const float*)d_in[13];
  const float* b2 = (const float*)d_in[14];

  const int IN = 128;
  const int Nn = in_sizes[0] / IN;
  const int E = in_sizes[1];
  const int ETP = E + 4 * Nn;

  char* ws = (char*)d_ws;
  size_t off = 0;
  auto alloc = [&](size_t bytes) {
    char* p = ws + off;
    off += (bytes + 255) & ~(size_t)255;
    return p;
  };
  ushort* feat = (ushort*)alloc(((size_t)Nn + 1) * 256 * 2);  // +sentinel row
  ushort* h1 = (ushort*)alloc((size_t)Nn * 256 * 2);
  ushort* h2 = (ushort*)alloc((size_t)Nn * 256 * 2);
  ushort* a0 = (ushort*)alloc((size_t)Nn * 128 * 2);
  ushort* Wt0 = (ushort*)alloc((size_t)256 * 128 * 2);
  ushort* Wt1 = (ushort*)alloc((size_t)256 * 256 * 2);
  ushort* Wt2 = (ushort*)alloc((size_t)64 * 256 * 2);
  float* el4 = (float*)alloc(((size_t)Nn + 1) * 4 * 4);
  float* er4 = (float*)alloc((size_t)Nn * 4 * 4);
  float* el1 = (float*)alloc(((size_t)Nn + 1) * 4);
  float* er1 = (float*)alloc((size_t)Nn * 4);
  int* row_ptr = (int*)alloc(((size_t)Nn + 1) * 4);
  int* cnt = (int*)alloc((size_t)Nn * 4);
  int* cursor = (int*)alloc((size_t)Nn * 4);
  int* esrc = (int*)alloc((size_t)ETP * 4);
  int* partials = (int*)alloc((size_t)1024 * 4);
  (void)ws_size;
  (void)n_in;
  (void)out_size;

  // prep: cvt + weight transposes + cnt zero + sentinels, one launch
  const int n8 = Nn * 16;
  const int nbA = (n8 + 255) / 256;
  const int nbW = (32768 + 65536 + 16384 + 255) / 256;
  const int nbZ = (Nn + 1023) / 1024;
  prep_kernel<<<nbA + nbW + nbZ + 1, 256, 0, stream>>>(
      nf, a0, n8, nbA, W0, Wt0, W1, Wt1, W2, Wt2, nbW, cnt, Nn, nbZ,
      feat + (size_t)Nn * 256, el4, el1);

  // ---- Build padded CSR over dst (reused by all 3 layers) ----
  const int ET = E + Nn;
  const int nb = (Nn + 1023) / 1024;
  hist_kernel<<<(ET + 255) / 256, 256, 0, stream>>>(dst, cnt, E, Nn);
  scan_blocks_kernel<<<nb, 1024, 0, stream>>>(cnt, row_ptr, partials, Nn);
  scan_partials_kernel<<<1, 1024, 0, stream>>>(partials, row_ptr, nb, Nn);
  add_offsets_kernel<<<nb, 1024, 0, stream>>>(row_ptr, cursor, partials, Nn);
  scatter_kernel<<<(ET + 255) / 256, 256, 0, stream>>>(src, dst, cursor, esrc,
                                                       E, Nn);
  fill_pad_kernel<<<(Nn + 255) / 256, 256, 0, stream>>>(cursor, row_ptr, esrc,
                                                        Nn);

  const int waves_grid = (Nn * 64 + 255) / 256;

  // Layer 0: [N,128] -> [N,256]  (attn fused into GEMM epilogue)
  {
    dim3 gg((Nn + 127) / 128, 2);
    gemm_mfma<128, true><<<gg, 256, 0, stream>>>(a0, Wt0, feat, Nn, 128, 256,
                                                 al0, ar0, el4, er4);
    agg_fused_h4<<<waves_grid, 256, 0, stream>>>(row_ptr, esrc, el4, er4, feat,
                                                 b0, h1, Nn);
  }
  // Layer 1: [N,256] -> [N,256]
  {
    dim3 gg((Nn + 127) / 128, 2);
    gemm_mfma<128, true><<<gg, 256, 0, stream>>>(h1, Wt1, feat, Nn, 256, 256,
                                                 al1, ar1, el4, er4);
    agg_fused_h4<<<waves_grid, 256, 0, stream>>>(row_ptr, esrc, el4, er4, feat,
                                                 b1, h2, Nn);
  }
  // Layer 2: [N,256] -> [N,64]
  {
    dim3 gg((Nn + 127) / 128, 1);
    gemm_mfma<64, false><<<gg, 256, 0, stream>>>(h2, Wt2, feat, Nn, 256, 64,
                                                 nullptr, nullptr, nullptr,
                                                 nullptr);
    attn_coef_h1<<<(Nn * 16 + 255) / 256, 256, 0, stream>>>(feat, al2, ar2,
                                                            el1, er1, Nn);
    agg_fused_h1<<<(Nn * 32 + 255) / 256, 256, 0, stream>>>(
        row_ptr, esrc, el1, er1, feat, b2, (float*)d_out, Nn);
  }
}